// Round 1
// baseline (2515.287 us; speedup 1.0000x reference)
//
#include <hip/hip_runtime.h>
#include <hip/hip_bf16.h>
#include <math.h>

typedef __bf16 bf16_t;
typedef __bf16 bf16x8 __attribute__((ext_vector_type(8)));
typedef float  f32x4  __attribute__((ext_vector_type(4)));

#define AS1 __attribute__((address_space(1)))
#define AS3 __attribute__((address_space(3)))

__device__ __forceinline__ void gload_lds16(const void* g, void* l) {
  __builtin_amdgcn_global_load_lds((const AS1 void*)g, (AS3 void*)l, 16, 0, 0);
}

static constexpr int N_ROWS = 8192;
static constexpr int DDIM   = 4096;
static constexpr int KEXP   = 8;
static constexpr int FHID   = 1024;
static constexpr int KD     = 8192;   // inner dim of both GEMMs (2D and K*F)

// ---------------- routing: weights = softmax(h_mask @ Wr^T + br) ----------------
__global__ __launch_bounds__(256)
void routing_kernel(const float* __restrict__ hm, const float* __restrict__ Wr,
                    const float* __restrict__ br, float* __restrict__ wgt) {
  const int n = blockIdx.x;
  const int t = threadIdx.x;
  const int wid = t >> 6;
  const float4* row = (const float4*)(hm + (size_t)n * DDIM);
  float4 x[4];
#pragma unroll
  for (int j = 0; j < 4; ++j) x[j] = row[t + j * 256];
  __shared__ float red[KEXP][4];
  float part[KEXP];
#pragma unroll
  for (int k = 0; k < KEXP; ++k) {
    const float4* wr = (const float4*)(Wr + (size_t)k * DDIM);
    float s = 0.f;
#pragma unroll
    for (int j = 0; j < 4; ++j) {
      float4 w4 = wr[t + j * 256];
      s += x[j].x * w4.x + x[j].y * w4.y + x[j].z * w4.z + x[j].w * w4.w;
    }
#pragma unroll
    for (int off = 32; off > 0; off >>= 1) s += __shfl_down(s, off);
    part[k] = s;
  }
  if ((t & 63) == 0) {
#pragma unroll
    for (int k = 0; k < KEXP; ++k) red[k][wid] = part[k];
  }
  __syncthreads();
  if (t == 0) {
    float lg[KEXP];
    float mx = -1e30f;
#pragma unroll
    for (int k = 0; k < KEXP; ++k) {
      lg[k] = red[k][0] + red[k][1] + red[k][2] + red[k][3] + br[k];
      mx = fmaxf(mx, lg[k]);
    }
    float sum = 0.f;
#pragma unroll
    for (int k = 0; k < KEXP; ++k) { lg[k] = expf(lg[k] - mx); sum += lg[k]; }
    float inv = 1.f / sum;
#pragma unroll
    for (int k = 0; k < KEXP; ++k) wgt[(size_t)n * KEXP + k] = lg[k] * inv;
  }
}

// ---------------- conversions to bf16 ----------------
__device__ __forceinline__ bf16x8 cvt8(float4 f0, float4 f1) {
  bf16x8 o;
  o[0] = (bf16_t)f0.x; o[1] = (bf16_t)f0.y; o[2] = (bf16_t)f0.z; o[3] = (bf16_t)f0.w;
  o[4] = (bf16_t)f1.x; o[5] = (bf16_t)f1.y; o[6] = (bf16_t)f1.z; o[7] = (bf16_t)f1.w;
  return o;
}

// A[n][0:4096]=h_anchor, A[n][4096:8192]=h_mask   (concat, bf16)
__global__ __launch_bounds__(256)
void conv_cond_kernel(const float* __restrict__ ha, const float* __restrict__ hm,
                      bf16_t* __restrict__ A) {
  size_t c = (size_t)blockIdx.x * 256 + threadIdx.x;  // chunk of 8 elements
  int n   = (int)(c >> 10);                           // 1024 chunks per row of 8192
  int pos = ((int)c & 1023) * 8;
  const float* src = (pos < DDIM) ? ha + (size_t)n * DDIM + pos
                                  : hm + (size_t)n * DDIM + (pos - DDIM);
  float4 f0 = ((const float4*)src)[0];
  float4 f1 = ((const float4*)src)[1];
  *(bf16x8*)(A + c * 8) = cvt8(f0, f1);
}

// straight fp32 -> bf16 cast (W1: already [K*F][2D] row-major)
__global__ __launch_bounds__(256)
void conv_cast_kernel(const float* __restrict__ in, bf16_t* __restrict__ out) {
  size_t c = (size_t)blockIdx.x * 256 + threadIdx.x;
  float4 f0 = ((const float4*)(in + c * 8))[0];
  float4 f1 = ((const float4*)(in + c * 8))[1];
  *(bf16x8*)(out + c * 8) = cvt8(f0, f1);
}

// W2[k][d][f] -> B2[d][k*F+f]  (bf16)
__global__ __launch_bounds__(256)
void conv_w2_kernel(const float* __restrict__ W2, bf16_t* __restrict__ B2) {
  size_t c = (size_t)blockIdx.x * 256 + threadIdx.x;  // over K*D*F/8
  int f8 = (int)(c & 127);
  int d  = (int)((c >> 7) & 4095);
  int k  = (int)(c >> 19);
  const float* src = W2 + ((size_t)k * DDIM + d) * FHID + f8 * 8;
  float4 f0 = ((const float4*)src)[0];
  float4 f1 = ((const float4*)src)[1];
  *(bf16x8*)(B2 + (size_t)d * KD + k * FHID + f8 * 8) = cvt8(f0, f1);
}

// ---------------- GEMM: C = A @ B^T, A [M][8192] bf16, B [Ncols][8192] bf16 ----------------
// MODE 1: epilogue = +b1, exact GELU, *w[n][col>>10], store bf16 (H1s)
// MODE 2: epilogue = + sum_k w[n][k]*b2[k][col], store fp32 (out)
template <int MODE>
__global__ __launch_bounds__(256, 2)
void gemm_kernel(const bf16_t* __restrict__ A, const bf16_t* __restrict__ B,
                 void* __restrict__ Cout, const float* __restrict__ bias,
                 const float* __restrict__ wgt, int Ncols) {
  constexpr int BM = 128, BN = 128, BK = 32;
  __shared__ bf16_t As[BM * BK];  // row-major [128][32]
  __shared__ bf16_t Bs[BN * BK];

  const int tid  = threadIdx.x;
  const int wid  = tid >> 6;
  const int lane = tid & 63;

  const int nbn = Ncols / BN;
  const int nwg = gridDim.x;
  const int cpx = nwg >> 3;                      // nwg % 8 == 0 for all our grids
  const int bid = blockIdx.x;
  const int swz = (bid & 7) * cpx + (bid >> 3);  // XCD-aware bijective swizzle
  const int bm = swz / nbn;
  const int bn = swz % nbn;

  const int wr = wid >> 1, wc = wid & 1;

  // staging: 16 chunks of 1KB (8 A, 8 B); each wave issues 4 global_load_lds x16B
  const bf16_t* gp[4];
  bf16_t* lp[4];
  {
    const int rsub = lane >> 2;        // 0..15 within chunk
    const int csub = (lane & 3) * 8;   // element column
#pragma unroll
    for (int i = 0; i < 4; ++i) {
      int c = wid * 4 + i;
      if (c < 8) {
        gp[i] = A + (size_t)(bm * BM + c * 16 + rsub) * KD + csub;
        lp[i] = As + c * 512;          // wave-uniform LDS base
      } else {
        gp[i] = B + (size_t)(bn * BN + (c - 8) * 16 + rsub) * KD + csub;
        lp[i] = Bs + (c - 8) * 512;
      }
    }
  }

  f32x4 zero = {0.f, 0.f, 0.f, 0.f};
  f32x4 acc[4][4];
#pragma unroll
  for (int mi = 0; mi < 4; ++mi)
#pragma unroll
    for (int ni = 0; ni < 4; ++ni) acc[mi][ni] = zero;

  const int aoff = (wr * 64 + (lane & 15)) * BK + ((lane >> 4) * 8);
  const int boff = (wc * 64 + (lane & 15)) * BK + ((lane >> 4) * 8);

  for (int kt = 0; kt < KD / BK; ++kt) {
#pragma unroll
    for (int i = 0; i < 4; ++i) gload_lds16(gp[i], (void*)lp[i]);
#pragma unroll
    for (int i = 0; i < 4; ++i) gp[i] += BK;
    __syncthreads();
    bf16x8 a[4], b[4];
#pragma unroll
    for (int mi = 0; mi < 4; ++mi) a[mi] = *(const bf16x8*)(As + aoff + mi * 16 * BK);
#pragma unroll
    for (int ni = 0; ni < 4; ++ni) b[ni] = *(const bf16x8*)(Bs + boff + ni * 16 * BK);
#pragma unroll
    for (int mi = 0; mi < 4; ++mi)
#pragma unroll
      for (int ni = 0; ni < 4; ++ni)
        acc[mi][ni] = __builtin_amdgcn_mfma_f32_16x16x32_bf16(a[mi], b[ni], acc[mi][ni], 0, 0, 0);
    __syncthreads();
  }

  // C/D fragment layout: row = (lane>>4)*4 + r, col = lane&15  [measured m89/m91]
  const int grow0 = bm * BM + wr * 64 + ((lane >> 4) << 2);
  const int gcol0 = bn * BN + wc * 64 + (lane & 15);

  if constexpr (MODE == 1) {
    bf16_t* __restrict__ H = (bf16_t*)Cout;
    const int kexp = (bn * BN) >> 10;  // expert is block-uniform (128 | 1024)
    float wn[4][4];
#pragma unroll
    for (int mi = 0; mi < 4; ++mi)
#pragma unroll
      for (int r = 0; r < 4; ++r)
        wn[mi][r] = wgt[(size_t)(grow0 + mi * 16 + r) * KEXP + kexp];
#pragma unroll
    for (int ni = 0; ni < 4; ++ni) {
      int col = gcol0 + ni * 16;
      float bv = bias[col];
#pragma unroll
      for (int mi = 0; mi < 4; ++mi)
#pragma unroll
        for (int r = 0; r < 4; ++r) {
          int n = grow0 + mi * 16 + r;
          float x = acc[mi][ni][r] + bv;
          float g = 0.5f * x * (1.f + erff(x * 0.70710678118654752f));  // exact GELU
          H[(size_t)n * KD + col] = (bf16_t)(g * wn[mi][r]);
        }
    }
  } else {
    float* __restrict__ O = (float*)Cout;
    float bcol[4][KEXP];
#pragma unroll
    for (int ni = 0; ni < 4; ++ni)
#pragma unroll
      for (int k = 0; k < KEXP; ++k)
        bcol[ni][k] = bias[(size_t)k * Ncols + gcol0 + ni * 16];
#pragma unroll
    for (int mi = 0; mi < 4; ++mi)
#pragma unroll
      for (int r = 0; r < 4; ++r) {
        int n = grow0 + mi * 16 + r;
        float w8[KEXP];
#pragma unroll
        for (int k = 0; k < KEXP; ++k) w8[k] = wgt[(size_t)n * KEXP + k];
#pragma unroll
        for (int ni = 0; ni < 4; ++ni) {
          float bb = 0.f;
#pragma unroll
          for (int k = 0; k < KEXP; ++k) bb += w8[k] * bcol[ni][k];
          O[(size_t)n * Ncols + gcol0 + ni * 16] = acc[mi][ni][r] + bb;
        }
      }
  }
}

extern "C" void kernel_launch(void* const* d_in, const int* in_sizes, int n_in,
                              void* d_out, int out_size, void* d_ws, size_t ws_size,
                              hipStream_t stream) {
  const float* h_anchor = (const float*)d_in[0];
  const float* h_mask   = (const float*)d_in[1];
  const float* Wr       = (const float*)d_in[2];
  const float* br       = (const float*)d_in[3];
  const float* W1       = (const float*)d_in[4];
  const float* b1       = (const float*)d_in[5];
  const float* W2       = (const float*)d_in[6];
  const float* b2       = (const float*)d_in[7];
  float* out = (float*)d_out;

  char* ws = (char*)d_ws;
  bf16_t* Abf  = (bf16_t*)(ws);                       // [8192][8192] bf16 = 128 MB
  bf16_t* W1bf = (bf16_t*)(ws + ((size_t)128 << 20)); // [8192][8192] bf16 = 128 MB
  bf16_t* W2bf = (bf16_t*)(ws + ((size_t)256 << 20)); // [4096][8192] bf16 =  64 MB
  bf16_t* H1s  = (bf16_t*)(ws + ((size_t)320 << 20)); // [8192][8192] bf16 = 128 MB
  float*  wgt  = (float*) (ws + ((size_t)448 << 20)); // [8192][8]   fp32 = 256 KB

  routing_kernel<<<N_ROWS, 256, 0, stream>>>(h_mask, Wr, br, wgt);
  conv_cond_kernel<<<(N_ROWS * KD / 8) / 256, 256, 0, stream>>>(h_anchor, h_mask, Abf);
  conv_cast_kernel<<<(KEXP * FHID * 2 * DDIM / 8) / 256, 256, 0, stream>>>(W1, W1bf);
  conv_w2_kernel<<<(KEXP * DDIM * FHID / 8) / 256, 256, 0, stream>>>(W2, W2bf);

  gemm_kernel<1><<<(N_ROWS / 128) * (KD / 128), 256, 0, stream>>>(
      Abf, W1bf, (void*)H1s, b1, wgt, 8192);
  gemm_kernel<2><<<(N_ROWS / 128) * (DDIM / 128), 256, 0, stream>>>(
      H1s, W2bf, (void*)out, b2, wgt, 4096);
}

// Round 2
// 2129.735 us; speedup vs baseline: 1.1810x; 1.1810x over previous
//
#include <hip/hip_runtime.h>
#include <hip/hip_bf16.h>
#include <math.h>

typedef __bf16 bf16_t;
typedef __bf16 bf16x8 __attribute__((ext_vector_type(8)));
typedef float  f32x4  __attribute__((ext_vector_type(4)));

#define AS1 __attribute__((address_space(1)))
#define AS3 __attribute__((address_space(3)))

__device__ __forceinline__ void gload_lds16(const bf16_t* g, char* l) {
  __builtin_amdgcn_global_load_lds((const AS1 void*)g, (AS3 void*)l, 16, 0, 0);
}

static constexpr int N_ROWS = 8192;
static constexpr int DDIM   = 4096;
static constexpr int KEXP   = 8;
static constexpr int FHID   = 1024;
static constexpr int KD     = 8192;   // inner dim of both GEMMs (2D and K*F)

// ---------------- routing: weights = softmax(h_mask @ Wr^T + br) ----------------
__global__ __launch_bounds__(256)
void routing_kernel(const float* __restrict__ hm, const float* __restrict__ Wr,
                    const float* __restrict__ br, float* __restrict__ wgt) {
  const int n = blockIdx.x;
  const int t = threadIdx.x;
  const int wid = t >> 6;
  const float4* row = (const float4*)(hm + (size_t)n * DDIM);
  float4 x[4];
#pragma unroll
  for (int j = 0; j < 4; ++j) x[j] = row[t + j * 256];
  __shared__ float red[KEXP][4];
  float part[KEXP];
#pragma unroll
  for (int k = 0; k < KEXP; ++k) {
    const float4* wr = (const float4*)(Wr + (size_t)k * DDIM);
    float s = 0.f;
#pragma unroll
    for (int j = 0; j < 4; ++j) {
      float4 w4 = wr[t + j * 256];
      s += x[j].x * w4.x + x[j].y * w4.y + x[j].z * w4.z + x[j].w * w4.w;
    }
#pragma unroll
    for (int off = 32; off > 0; off >>= 1) s += __shfl_down(s, off);
    part[k] = s;
  }
  if ((t & 63) == 0) {
#pragma unroll
    for (int k = 0; k < KEXP; ++k) red[k][wid] = part[k];
  }
  __syncthreads();
  if (t == 0) {
    float lg[KEXP];
    float mx = -1e30f;
#pragma unroll
    for (int k = 0; k < KEXP; ++k) {
      lg[k] = red[k][0] + red[k][1] + red[k][2] + red[k][3] + br[k];
      mx = fmaxf(mx, lg[k]);
    }
    float sum = 0.f;
#pragma unroll
    for (int k = 0; k < KEXP; ++k) { lg[k] = expf(lg[k] - mx); sum += lg[k]; }
    float inv = 1.f / sum;
#pragma unroll
    for (int k = 0; k < KEXP; ++k) wgt[(size_t)n * KEXP + k] = lg[k] * inv;
  }
}

// ---------------- conversions to bf16 ----------------
__device__ __forceinline__ bf16x8 cvt8(float4 f0, float4 f1) {
  bf16x8 o;
  o[0] = (bf16_t)f0.x; o[1] = (bf16_t)f0.y; o[2] = (bf16_t)f0.z; o[3] = (bf16_t)f0.w;
  o[4] = (bf16_t)f1.x; o[5] = (bf16_t)f1.y; o[6] = (bf16_t)f1.z; o[7] = (bf16_t)f1.w;
  return o;
}

// A[n][0:4096]=h_anchor, A[n][4096:8192]=h_mask   (concat, bf16)
__global__ __launch_bounds__(256)
void conv_cond_kernel(const float* __restrict__ ha, const float* __restrict__ hm,
                      bf16_t* __restrict__ A) {
  size_t c = (size_t)blockIdx.x * 256 + threadIdx.x;  // chunk of 8 elements
  int n   = (int)(c >> 10);                           // 1024 chunks per row of 8192
  int pos = ((int)c & 1023) * 8;
  const float* src = (pos < DDIM) ? ha + (size_t)n * DDIM + pos
                                  : hm + (size_t)n * DDIM + (pos - DDIM);
  float4 f0 = ((const float4*)src)[0];
  float4 f1 = ((const float4*)src)[1];
  *(bf16x8*)(A + c * 8) = cvt8(f0, f1);
}

// straight fp32 -> bf16 cast (W1: already [K*F][2D] row-major)
__global__ __launch_bounds__(256)
void conv_cast_kernel(const float* __restrict__ in, bf16_t* __restrict__ out) {
  size_t c = (size_t)blockIdx.x * 256 + threadIdx.x;
  float4 f0 = ((const float4*)(in + c * 8))[0];
  float4 f1 = ((const float4*)(in + c * 8))[1];
  *(bf16x8*)(out + c * 8) = cvt8(f0, f1);
}

// W2[k][d][f] -> B2[d][k*F+f]  (bf16)
__global__ __launch_bounds__(256)
void conv_w2_kernel(const float* __restrict__ W2, bf16_t* __restrict__ B2) {
  size_t c = (size_t)blockIdx.x * 256 + threadIdx.x;  // over K*D*F/8
  int f8 = (int)(c & 127);
  int d  = (int)((c >> 7) & 4095);
  int k  = (int)(c >> 19);
  const float* src = W2 + ((size_t)k * DDIM + d) * FHID + f8 * 8;
  float4 f0 = ((const float4*)src)[0];
  float4 f1 = ((const float4*)src)[1];
  *(bf16x8*)(B2 + (size_t)d * KD + k * FHID + f8 * 8) = cvt8(f0, f1);
}

// ---------------- 256x256 phase-split GEMM: C = A @ B^T over KD=8192 ----------------
// BK=32, 4-deep LDS pipeline (4 x 32KB buffers), 8 waves (2Mx4N), counted vmcnt(8).
// LDS swizzle (T2): involution  byte ^= ((byte>>7)&3)<<4  (16B-slot XOR row bits 1..2)
// applied to BOTH the global-source pre-swizzle (linear global_load_lds dest) and the
// ds_read addresses (rule #21).
// MODE 1: epilogue = +b1, exact GELU, *w[n][col>>10], store bf16 (H1s)
// MODE 2: epilogue = + sum_k w[n][k]*b2[k][col], store fp32 (out)
template <int MODE, int NCOLS>
__global__ __launch_bounds__(512, 2)
void gemm256_kernel(const bf16_t* __restrict__ Amat, const bf16_t* __restrict__ Bmat,
                    void* __restrict__ Cout, const float* __restrict__ bias,
                    const float* __restrict__ wgt) {
  constexpr int BM = 256, BN = 256, BK = 32;
  constexpr int NT = KD / BK;            // 256 K-tiles
  constexpr int BUFB = 32768;            // bytes per buffer (A 16KB + B 16KB)
  __shared__ char lds_raw[4 * BUFB];     // 128 KB

  const int tid  = threadIdx.x;
  const int wid  = tid >> 6;
  const int lane = tid & 63;
  const int wr   = wid >> 2;             // 0..1  (M half)
  const int wc   = wid & 3;              // 0..3  (N quarter)

  constexpr int nbn = NCOLS / BN;
  const int nwg = gridDim.x;
  const int cpx = nwg >> 3;
  const int bid = blockIdx.x;
  const int swz = (bid & 7) * cpx + (bid >> 3);  // XCD-aware bijective swizzle
  const int bm = swz / nbn;
  const int bn = swz % nbn;
  const int arow0 = bm * BM;
  const int brow0 = bn * BN;

  // ---- staging descriptors: per-thread global src (inverse-swizzled), uniform LDS dst
  const bf16_t* srcA[2];
  const bf16_t* srcB[2];
  int dstA[2], dstB[2];
#pragma unroll
  for (int i = 0; i < 2; ++i) {
    int p    = i * 8192 + tid * 16;                 // phys byte within region
    int l    = p ^ (((p >> 7) & 3) << 4);           // logical byte (involution)
    int lrow = l >> 6;
    int lcol = (l & 63) >> 1;
    srcA[i] = Amat + (size_t)(arow0 + lrow) * KD + lcol;
    srcB[i] = Bmat + (size_t)(brow0 + lrow) * KD + lcol;
    dstA[i] = i * 8192 + (wid << 10);               // wave-uniform (no lane part)
    dstB[i] = 16384 + dstA[i];
  }

  // ---- ds_read byte offsets (swizzled)
  const int j = lane >> 4;
  int aoffB[8], boffB[4];
#pragma unroll
  for (int mi = 0; mi < 8; ++mi) {
    int row = wr * 128 + mi * 16 + (lane & 15);
    aoffB[mi] = row * 64 + ((j ^ ((row >> 1) & 3)) << 4);
  }
#pragma unroll
  for (int ni = 0; ni < 4; ++ni) {
    int row = wc * 64 + ni * 16 + (lane & 15);
    boffB[ni] = 16384 + row * 64 + ((j ^ ((row >> 1) & 3)) << 4);
  }

  f32x4 acc[8][4];
  f32x4 zero = {0.f, 0.f, 0.f, 0.f};
#pragma unroll
  for (int mi = 0; mi < 8; ++mi)
#pragma unroll
    for (int ni = 0; ni < 4; ++ni) acc[mi][ni] = zero;

  // ---- prologue: stage tiles 0..2 into buffers 0..2 (A0,A1,B0,B1 each)
#pragma unroll
  for (int pt = 0; pt < 3; ++pt) {
    char* base = lds_raw + pt * BUFB;
#pragma unroll
    for (int i = 0; i < 2; ++i) gload_lds16(srcA[i] + (size_t)pt * BK, base + dstA[i]);
#pragma unroll
    for (int i = 0; i < 2; ++i) gload_lds16(srcB[i] + (size_t)pt * BK, base + dstB[i]);
  }

  // ---- main loop: per tile, 2 phases of {ds_read | stage t+3 | barrier | MFMA x16}
  for (int t = 0; t < NT; ++t) {
    const int bufo = (t & 3) * BUFB;
    char* sbase = lds_raw + ((t + 3) & 3) * BUFB;

    asm volatile("s_waitcnt vmcnt(8)" ::: "memory");  // tile t landed (t+1,t+2 in flight)
    __builtin_amdgcn_s_barrier();

    // phase 0: A frags 0..3 + all B frags; stage A(t+3); MFMA quadrant
    bf16x8 a0[4], bb[4];
#pragma unroll
    for (int mi = 0; mi < 4; ++mi)
      a0[mi] = *(const bf16x8*)(lds_raw + bufo + aoffB[mi]);
#pragma unroll
    for (int ni = 0; ni < 4; ++ni)
      bb[ni] = *(const bf16x8*)(lds_raw + bufo + boffB[ni]);
    if (t + 3 < NT) {
#pragma unroll
      for (int i = 0; i < 2; ++i) gload_lds16(srcA[i] + (size_t)(t + 3) * BK, sbase + dstA[i]);
    }
    __builtin_amdgcn_sched_barrier(0);
    __builtin_amdgcn_s_barrier();
    asm volatile("s_waitcnt lgkmcnt(0)" ::: "memory");
    __builtin_amdgcn_sched_barrier(0);
    __builtin_amdgcn_s_setprio(1);
#pragma unroll
    for (int mi = 0; mi < 4; ++mi)
#pragma unroll
      for (int ni = 0; ni < 4; ++ni)
        acc[mi][ni] = __builtin_amdgcn_mfma_f32_16x16x32_bf16(a0[mi], bb[ni], acc[mi][ni], 0, 0, 0);
    __builtin_amdgcn_s_setprio(0);
    __builtin_amdgcn_sched_barrier(0);

    // phase 1: A frags 4..7 (B reused in regs); stage B(t+3); MFMA quadrant
    bf16x8 a1[4];
#pragma unroll
    for (int mi = 0; mi < 4; ++mi)
      a1[mi] = *(const bf16x8*)(lds_raw + bufo + aoffB[mi + 4]);
    if (t + 3 < NT) {
#pragma unroll
      for (int i = 0; i < 2; ++i) gload_lds16(srcB[i] + (size_t)(t + 3) * BK, sbase + dstB[i]);
    }
    __builtin_amdgcn_sched_barrier(0);
    __builtin_amdgcn_s_barrier();
    asm volatile("s_waitcnt lgkmcnt(0)" ::: "memory");
    __builtin_amdgcn_sched_barrier(0);
    __builtin_amdgcn_s_setprio(1);
#pragma unroll
    for (int mi = 0; mi < 4; ++mi)
#pragma unroll
      for (int ni = 0; ni < 4; ++ni)
        acc[mi + 4][ni] = __builtin_amdgcn_mfma_f32_16x16x32_bf16(a1[mi], bb[ni], acc[mi + 4][ni], 0, 0, 0);
    __builtin_amdgcn_s_setprio(0);
    __builtin_amdgcn_sched_barrier(0);
  }

  // ---- epilogue.  C/D layout: row = (lane>>4)*4 + r, col = lane&15  [m89/m91]
  const int grow0 = arow0 + wr * 128 + ((lane >> 4) << 2);
  const int gcol0 = brow0 + wc * 64 + (lane & 15);

  if constexpr (MODE == 1) {
    bf16_t* __restrict__ H = (bf16_t*)Cout;
    const int kexp = brow0 >> 10;  // expert is block-uniform (256 | 1024)
#pragma unroll
    for (int mi = 0; mi < 8; ++mi) {
      float wn[4];
#pragma unroll
      for (int r = 0; r < 4; ++r)
        wn[r] = wgt[(size_t)(grow0 + mi * 16 + r) * KEXP + kexp];
#pragma unroll
      for (int ni = 0; ni < 4; ++ni) {
        int col = gcol0 + ni * 16;
        float bv = bias[col];
#pragma unroll
        for (int r = 0; r < 4; ++r) {
          int n = grow0 + mi * 16 + r;
          float x = acc[mi][ni][r] + bv;
          float g = 0.5f * x * (1.f + erff(x * 0.70710678118654752f));  // exact GELU
          H[(size_t)n * KD + col] = (bf16_t)(g * wn[r]);
        }
      }
    }
  } else {
    float* __restrict__ O = (float*)Cout;
    float bcol[4][KEXP];
#pragma unroll
    for (int ni = 0; ni < 4; ++ni)
#pragma unroll
      for (int k = 0; k < KEXP; ++k)
        bcol[ni][k] = bias[(size_t)k * NCOLS + gcol0 + ni * 16];
#pragma unroll
    for (int mi = 0; mi < 8; ++mi)
#pragma unroll
      for (int r = 0; r < 4; ++r) {
        int n = grow0 + mi * 16 + r;
        const float4* wp = (const float4*)(wgt + (size_t)n * KEXP);
        float4 wa = wp[0], wb = wp[1];
        float w8[KEXP] = {wa.x, wa.y, wa.z, wa.w, wb.x, wb.y, wb.z, wb.w};
#pragma unroll
        for (int ni = 0; ni < 4; ++ni) {
          float bb2 = 0.f;
#pragma unroll
          for (int k = 0; k < KEXP; ++k) bb2 += w8[k] * bcol[ni][k];
          O[(size_t)n * NCOLS + gcol0 + ni * 16] = acc[mi][ni][r] + bb2;
        }
      }
  }
}

extern "C" void kernel_launch(void* const* d_in, const int* in_sizes, int n_in,
                              void* d_out, int out_size, void* d_ws, size_t ws_size,
                              hipStream_t stream) {
  const float* h_anchor = (const float*)d_in[0];
  const float* h_mask   = (const float*)d_in[1];
  const float* Wr       = (const float*)d_in[2];
  const float* br       = (const float*)d_in[3];
  const float* W1       = (const float*)d_in[4];
  const float* b1       = (const float*)d_in[5];
  const float* W2       = (const float*)d_in[6];
  const float* b2       = (const float*)d_in[7];
  float* out = (float*)d_out;

  char* ws = (char*)d_ws;
  bf16_t* Abf  = (bf16_t*)(ws);                       // [8192][8192] bf16 = 128 MB
  bf16_t* W1bf = (bf16_t*)(ws + ((size_t)128 << 20)); // [8192][8192] bf16 = 128 MB
  bf16_t* W2bf = (bf16_t*)(ws + ((size_t)256 << 20)); // [4096][8192] bf16 =  64 MB
  bf16_t* H1s  = (bf16_t*)(ws + ((size_t)320 << 20)); // [8192][8192] bf16 = 128 MB
  float*  wgt  = (float*) (ws + ((size_t)448 << 20)); // [8192][8]   fp32 = 256 KB

  routing_kernel<<<N_ROWS, 256, 0, stream>>>(h_mask, Wr, br, wgt);
  conv_cond_kernel<<<(N_ROWS * KD / 8) / 256, 256, 0, stream>>>(h_anchor, h_mask, Abf);
  conv_cast_kernel<<<(KEXP * FHID * 2 * DDIM / 8) / 256, 256, 0, stream>>>(W1, W1bf);
  conv_w2_kernel<<<(KEXP * DDIM * FHID / 8) / 256, 256, 0, stream>>>(W2, W2bf);

  gemm256_kernel<1, 8192><<<(N_ROWS / 256) * (KD / 256), 512, 0, stream>>>(
      Abf, W1bf, (void*)H1s, b1, wgt);
  gemm256_kernel<2, 4096><<<(N_ROWS / 256) * (DDIM / 256), 512, 0, stream>>>(
      H1s, W2bf, (void*)out, b2, wgt);
}

// Round 4
// 1642.480 us; speedup vs baseline: 1.5314x; 1.2967x over previous
//
#include <hip/hip_runtime.h>
#include <hip/hip_bf16.h>
#include <math.h>

typedef __bf16 bf16_t;
typedef __bf16 bf16x8 __attribute__((ext_vector_type(8)));
typedef float  f32x4  __attribute__((ext_vector_type(4)));

#define AS1 __attribute__((address_space(1)))
#define AS3 __attribute__((address_space(3)))

__device__ __forceinline__ void gload_lds16(const bf16_t* g, char* l) {
  __builtin_amdgcn_global_load_lds((const AS1 void*)g, (AS3 void*)l, 16, 0, 0);
}

static constexpr int N_ROWS = 8192;
static constexpr int DDIM   = 4096;
static constexpr int KEXP   = 8;
static constexpr int FHID   = 1024;
static constexpr int KD     = 8192;   // inner dim of both GEMMs (2D and K*F)

// ---------------- routing: weights = softmax(h_mask @ Wr^T + br) ----------------
__global__ __launch_bounds__(256)
void routing_kernel(const float* __restrict__ hm, const float* __restrict__ Wr,
                    const float* __restrict__ br, float* __restrict__ wgt) {
  const int n = blockIdx.x;
  const int t = threadIdx.x;
  const int wid = t >> 6;
  const float4* row = (const float4*)(hm + (size_t)n * DDIM);
  float4 x[4];
#pragma unroll
  for (int j = 0; j < 4; ++j) x[j] = row[t + j * 256];
  __shared__ float red[KEXP][4];
  float part[KEXP];
#pragma unroll
  for (int k = 0; k < KEXP; ++k) {
    const float4* wr = (const float4*)(Wr + (size_t)k * DDIM);
    float s = 0.f;
#pragma unroll
    for (int j = 0; j < 4; ++j) {
      float4 w4 = wr[t + j * 256];
      s += x[j].x * w4.x + x[j].y * w4.y + x[j].z * w4.z + x[j].w * w4.w;
    }
#pragma unroll
    for (int off = 32; off > 0; off >>= 1) s += __shfl_down(s, off);
    part[k] = s;
  }
  if ((t & 63) == 0) {
#pragma unroll
    for (int k = 0; k < KEXP; ++k) red[k][wid] = part[k];
  }
  __syncthreads();
  if (t == 0) {
    float lg[KEXP];
    float mx = -1e30f;
#pragma unroll
    for (int k = 0; k < KEXP; ++k) {
      lg[k] = red[k][0] + red[k][1] + red[k][2] + red[k][3] + br[k];
      mx = fmaxf(mx, lg[k]);
    }
    float sum = 0.f;
#pragma unroll
    for (int k = 0; k < KEXP; ++k) { lg[k] = expf(lg[k] - mx); sum += lg[k]; }
    float inv = 1.f / sum;
#pragma unroll
    for (int k = 0; k < KEXP; ++k) wgt[(size_t)n * KEXP + k] = lg[k] * inv;
  }
}

// ---------------- conversions to bf16 ----------------
__device__ __forceinline__ bf16x8 cvt8(float4 f0, float4 f1) {
  bf16x8 o;
  o[0] = (bf16_t)f0.x; o[1] = (bf16_t)f0.y; o[2] = (bf16_t)f0.z; o[3] = (bf16_t)f0.w;
  o[4] = (bf16_t)f1.x; o[5] = (bf16_t)f1.y; o[6] = (bf16_t)f1.z; o[7] = (bf16_t)f1.w;
  return o;
}

// A[n][0:4096]=h_anchor, A[n][4096:8192]=h_mask   (concat, bf16)
__global__ __launch_bounds__(256)
void conv_cond_kernel(const float* __restrict__ ha, const float* __restrict__ hm,
                      bf16_t* __restrict__ A) {
  size_t c = (size_t)blockIdx.x * 256 + threadIdx.x;  // chunk of 8 elements
  int n   = (int)(c >> 10);                           // 1024 chunks per row of 8192
  int pos = ((int)c & 1023) * 8;
  const float* src = (pos < DDIM) ? ha + (size_t)n * DDIM + pos
                                  : hm + (size_t)n * DDIM + (pos - DDIM);
  float4 f0 = ((const float4*)src)[0];
  float4 f1 = ((const float4*)src)[1];
  *(bf16x8*)(A + c * 8) = cvt8(f0, f1);
}

// straight fp32 -> bf16 cast (W1: already [K*F][2D] row-major)
__global__ __launch_bounds__(256)
void conv_cast_kernel(const float* __restrict__ in, bf16_t* __restrict__ out) {
  size_t c = (size_t)blockIdx.x * 256 + threadIdx.x;
  float4 f0 = ((const float4*)(in + c * 8))[0];
  float4 f1 = ((const float4*)(in + c * 8))[1];
  *(bf16x8*)(out + c * 8) = cvt8(f0, f1);
}

// W2[k][d][f] -> B2[d][k*F+f]  (bf16)
__global__ __launch_bounds__(256)
void conv_w2_kernel(const float* __restrict__ W2, bf16_t* __restrict__ B2) {
  size_t c = (size_t)blockIdx.x * 256 + threadIdx.x;  // over K*D*F/8
  int f8 = (int)(c & 127);
  int d  = (int)((c >> 7) & 4095);
  int k  = (int)(c >> 19);
  const float* src = W2 + ((size_t)k * DDIM + d) * FHID + f8 * 8;
  float4 f0 = ((const float4*)src)[0];
  float4 f1 = ((const float4*)src)[1];
  *(bf16x8*)(B2 + (size_t)d * KD + k * FHID + f8 * 8) = cvt8(f0, f1);
}

// ---------------- 256x256 phase-split GEMM: C = A @ B^T over KD=8192 ----------------
// BK=32, 4-deep LDS pipeline (4 x 32KB buffers), 8 waves (2Mx4N), counted vmcnt(8).
// LDS swizzle (T2): involution  byte ^= ((byte>>7)&3)<<4  applied on BOTH sides
// (inverse-swizzled global source + linear global_load_lds dest; swizzled ds_read).
// Staging is MODULAR ((t+3) & (NT-1), unconditional): keeps exactly 12 loads in
// flight at every top-of-loop so vmcnt(8) always retires precisely tile t's 4 loads.
// (The previous `if (t+3 < NT)` guard made vmcnt(8) a no-op for the last 2 tiles ->
// timing-dependent race caught by the harness tripwire in round 3.)
// Block-order remap: 256-block windows form a 16x16 output-tile square; each XCD's
// 32 blocks form a 4bm x 8bn sub-square. bid -> (w, cu, xcd), bijective.
// MODE 1: epilogue = +b1, exact GELU, *w[n][col>>10], store bf16 (H1s)
// MODE 2: epilogue = + sum_k w[n][k]*b2[k][col], store fp32 (out)
template <int MODE, int NCOLS>
__global__ __launch_bounds__(512, 2)
void gemm256_kernel(const bf16_t* __restrict__ Amat, const bf16_t* __restrict__ Bmat,
                    void* __restrict__ Cout, const float* __restrict__ bias,
                    const float* __restrict__ wgt) {
  constexpr int BM = 256, BN = 256, BK = 32;
  constexpr int NT = KD / BK;            // 256 K-tiles
  constexpr int BUFB = 32768;            // bytes per buffer (A 16KB + B 16KB)
  __shared__ char lds_raw[4 * BUFB];     // 128 KB

  const int tid  = threadIdx.x;
  const int wid  = tid >> 6;
  const int lane = tid & 63;
  const int wr   = wid >> 2;             // 0..1  (M half)
  const int wc   = wid & 3;              // 0..3  (N quarter)

  // ---- 2-D concurrency-window block remap (16x16 window, 4x8 per XCD)
  constexpr int NBN    = NCOLS / BN;     // 32 (GEMM1) or 16 (GEMM2)
  constexpr int NWIN_N = NBN / 16;       // 2 or 1
  const int bid = blockIdx.x;
  const int w   = bid >> 8;              // concurrency window index
  const int sl  = bid & 255;
  const int xcd = sl & 7;
  const int cu  = sl >> 3;               // 0..31 within XCD
  const int wm  = w / NWIN_N, wn = w % NWIN_N;
  const int bm  = wm * 16 + ((xcd >> 1) << 2) + (cu & 3);
  const int bn  = wn * 16 + ((xcd & 1) << 3) + (cu >> 2);
  const int arow0 = bm * BM;
  const int brow0 = bn * BN;

  // ---- staging descriptors: per-thread global src (inverse-swizzled), uniform LDS dst
  const bf16_t* srcA[2];
  const bf16_t* srcB[2];
  int dstA[2], dstB[2];
#pragma unroll
  for (int i = 0; i < 2; ++i) {
    int p    = i * 8192 + tid * 16;                 // phys byte within region
    int l    = p ^ (((p >> 7) & 3) << 4);           // logical byte (involution)
    int lrow = l >> 6;
    int lcol = (l & 63) >> 1;
    srcA[i] = Amat + (size_t)(arow0 + lrow) * KD + lcol;
    srcB[i] = Bmat + (size_t)(brow0 + lrow) * KD + lcol;
    dstA[i] = i * 8192 + (wid << 10);               // wave-uniform (no lane part)
    dstB[i] = 16384 + dstA[i];
  }

  // ---- ds_read byte offsets (swizzled)
  const int j = lane >> 4;
  int aoffB[8], boffB[4];
#pragma unroll
  for (int mi = 0; mi < 8; ++mi) {
    int row = wr * 128 + mi * 16 + (lane & 15);
    aoffB[mi] = row * 64 + ((j ^ ((row >> 1) & 3)) << 4);
  }
#pragma unroll
  for (int ni = 0; ni < 4; ++ni) {
    int row = wc * 64 + ni * 16 + (lane & 15);
    boffB[ni] = 16384 + row * 64 + ((j ^ ((row >> 1) & 3)) << 4);
  }

  f32x4 acc[8][4];
  f32x4 zero = {0.f, 0.f, 0.f, 0.f};
#pragma unroll
  for (int mi = 0; mi < 8; ++mi)
#pragma unroll
    for (int ni = 0; ni < 4; ++ni) acc[mi][ni] = zero;

  // ---- prologue: stage tiles 0..2 into buffers 0..2 (A0,A1,B0,B1 each)
#pragma unroll
  for (int pt = 0; pt < 3; ++pt) {
    char* base = lds_raw + pt * BUFB;
#pragma unroll
    for (int i = 0; i < 2; ++i) gload_lds16(srcA[i] + (size_t)pt * BK, base + dstA[i]);
#pragma unroll
    for (int i = 0; i < 2; ++i) gload_lds16(srcB[i] + (size_t)pt * BK, base + dstB[i]);
  }

  // ---- main loop: per tile, 2 phases of {ds_read | stage (t+3)%NT | barrier | MFMA x16}
  for (int t = 0; t < NT; ++t) {
    const int bufo = (t & 3) * BUFB;
    const int ts   = (t + 3) & (NT - 1);            // modular staging tile
    char* sbase = lds_raw + ((t + 3) & 3) * BUFB;

    asm volatile("s_waitcnt vmcnt(8)" ::: "memory");  // tile t landed (t+1,t+2 in flight)
    __builtin_amdgcn_s_barrier();

    // phase 0: A frags 0..3 + all B frags; stage A(ts); MFMA quadrant
    bf16x8 a0[4], bb[4];
#pragma unroll
    for (int mi = 0; mi < 4; ++mi)
      a0[mi] = *(const bf16x8*)(lds_raw + bufo + aoffB[mi]);
#pragma unroll
    for (int ni = 0; ni < 4; ++ni)
      bb[ni] = *(const bf16x8*)(lds_raw + bufo + boffB[ni]);
#pragma unroll
    for (int i = 0; i < 2; ++i) gload_lds16(srcA[i] + (size_t)ts * BK, sbase + dstA[i]);
    __builtin_amdgcn_sched_barrier(0);
    __builtin_amdgcn_s_barrier();
    asm volatile("s_waitcnt lgkmcnt(0)" ::: "memory");
    __builtin_amdgcn_sched_barrier(0);
    __builtin_amdgcn_s_setprio(1);
#pragma unroll
    for (int mi = 0; mi < 4; ++mi)
#pragma unroll
      for (int ni = 0; ni < 4; ++ni)
        acc[mi][ni] = __builtin_amdgcn_mfma_f32_16x16x32_bf16(a0[mi], bb[ni], acc[mi][ni], 0, 0, 0);
    __builtin_amdgcn_s_setprio(0);
    __builtin_amdgcn_sched_barrier(0);

    // phase 1: A frags 4..7 (B reused in regs); stage B(ts); MFMA quadrant
    bf16x8 a1[4];
#pragma unroll
    for (int mi = 0; mi < 4; ++mi)
      a1[mi] = *(const bf16x8*)(lds_raw + bufo + aoffB[mi + 4]);
#pragma unroll
    for (int i = 0; i < 2; ++i) gload_lds16(srcB[i] + (size_t)ts * BK, sbase + dstB[i]);
    __builtin_amdgcn_sched_barrier(0);
    __builtin_amdgcn_s_barrier();
    asm volatile("s_waitcnt lgkmcnt(0)" ::: "memory");
    __builtin_amdgcn_sched_barrier(0);
    __builtin_amdgcn_s_setprio(1);
#pragma unroll
    for (int mi = 0; mi < 4; ++mi)
#pragma unroll
      for (int ni = 0; ni < 4; ++ni)
        acc[mi + 4][ni] = __builtin_amdgcn_mfma_f32_16x16x32_bf16(a1[mi], bb[ni], acc[mi + 4][ni], 0, 0, 0);
    __builtin_amdgcn_s_setprio(0);
    __builtin_amdgcn_sched_barrier(0);
  }

  // ---- epilogue.  C/D layout: row = (lane>>4)*4 + r, col = lane&15  [m89/m91]
  const int grow0 = arow0 + wr * 128 + ((lane >> 4) << 2);
  const int gcol0 = brow0 + wc * 64 + (lane & 15);

  if constexpr (MODE == 1) {
    bf16_t* __restrict__ H = (bf16_t*)Cout;
    const int kexp = brow0 >> 10;  // expert is block-uniform (256 | 1024)
#pragma unroll
    for (int mi = 0; mi < 8; ++mi) {
      float wn4[4];
#pragma unroll
      for (int r = 0; r < 4; ++r)
        wn4[r] = wgt[(size_t)(grow0 + mi * 16 + r) * KEXP + kexp];
#pragma unroll
      for (int ni = 0; ni < 4; ++ni) {
        int col = gcol0 + ni * 16;
        float bv = bias[col];
#pragma unroll
        for (int r = 0; r < 4; ++r) {
          int n = grow0 + mi * 16 + r;
          float x = acc[mi][ni][r] + bv;
          float g = 0.5f * x * (1.f + erff(x * 0.70710678118654752f));  // exact GELU
          H[(size_t)n * KD + col] = (bf16_t)(g * wn4[r]);
        }
      }
    }
  } else {
    float* __restrict__ O = (float*)Cout;
    float bcol[4][KEXP];
#pragma unroll
    for (int ni = 0; ni < 4; ++ni)
#pragma unroll
      for (int k = 0; k < KEXP; ++k)
        bcol[ni][k] = bias[(size_t)k * NCOLS + gcol0 + ni * 16];
#pragma unroll
    for (int mi = 0; mi < 8; ++mi)
#pragma unroll
      for (int r = 0; r < 4; ++r) {
        int n = grow0 + mi * 16 + r;
        const float4* wp = (const float4*)(wgt + (size_t)n * KEXP);
        float4 wa = wp[0], wb = wp[1];
        float w8[KEXP] = {wa.x, wa.y, wa.z, wa.w, wb.x, wb.y, wb.z, wb.w};
#pragma unroll
        for (int ni = 0; ni < 4; ++ni) {
          float bb2 = 0.f;
#pragma unroll
          for (int k = 0; k < KEXP; ++k) bb2 += w8[k] * bcol[ni][k];
          O[(size_t)n * NCOLS + gcol0 + ni * 16] = acc[mi][ni][r] + bb2;
        }
      }
  }
}

extern "C" void kernel_launch(void* const* d_in, const int* in_sizes, int n_in,
                              void* d_out, int out_size, void* d_ws, size_t ws_size,
                              hipStream_t stream) {
  const float* h_anchor = (const float*)d_in[0];
  const float* h_mask   = (const float*)d_in[1];
  const float* Wr       = (const float*)d_in[2];
  const float* br       = (const float*)d_in[3];
  const float* W1       = (const float*)d_in[4];
  const float* b1       = (const float*)d_in[5];
  const float* W2       = (const float*)d_in[6];
  const float* b2       = (const float*)d_in[7];
  float* out = (float*)d_out;

  char* ws = (char*)d_ws;
  bf16_t* Abf  = (bf16_t*)(ws);                       // [8192][8192] bf16 = 128 MB
  bf16_t* W1bf = (bf16_t*)(ws + ((size_t)128 << 20)); // [8192][8192] bf16 = 128 MB
  bf16_t* W2bf = (bf16_t*)(ws + ((size_t)256 << 20)); // [4096][8192] bf16 =  64 MB
  bf16_t* H1s  = (bf16_t*)(ws + ((size_t)320 << 20)); // [8192][8192] bf16 = 128 MB
  float*  wgt  = (float*) (ws + ((size_t)448 << 20)); // [8192][8]   fp32 = 256 KB

  routing_kernel<<<N_ROWS, 256, 0, stream>>>(h_mask, Wr, br, wgt);
  conv_cond_kernel<<<(N_ROWS * KD / 8) / 256, 256, 0, stream>>>(h_anchor, h_mask, Abf);
  conv_cast_kernel<<<(KEXP * FHID * 2 * DDIM / 8) / 256, 256, 0, stream>>>(W1, W1bf);
  conv_w2_kernel<<<(KEXP * DDIM * FHID / 8) / 256, 256, 0, stream>>>(W2, W2bf);

  gemm256_kernel<1, 8192><<<(N_ROWS / 256) * (KD / 256), 512, 0, stream>>>(
      Abf, W1bf, (void*)H1s, b1, wgt);
  gemm256_kernel<2, 4096><<<(N_ROWS / 256) * (DDIM / 256), 512, 0, stream>>>(
      H1s, W2bf, (void*)out, b2, wgt);
}

// Round 5
// 1640.829 us; speedup vs baseline: 1.5329x; 1.0010x over previous
//
#include <hip/hip_runtime.h>
#include <hip/hip_bf16.h>
#include <math.h>

typedef __bf16 bf16_t;
typedef __bf16 bf16x8 __attribute__((ext_vector_type(8)));
typedef float  f32x4  __attribute__((ext_vector_type(4)));

#define AS1 __attribute__((address_space(1)))
#define AS3 __attribute__((address_space(3)))

__device__ __forceinline__ void gload_lds16(const bf16_t* g, char* l) {
  __builtin_amdgcn_global_load_lds((const AS1 void*)g, (AS3 void*)l, 16, 0, 0);
}

static constexpr int N_ROWS = 8192;
static constexpr int DDIM   = 4096;
static constexpr int KEXP   = 8;
static constexpr int FHID   = 1024;
static constexpr int KD     = 8192;   // inner dim of both GEMMs (2D and K*F)

// ---------------- routing: weights = softmax(h_mask @ Wr^T + br) ----------------
__global__ __launch_bounds__(256)
void routing_kernel(const float* __restrict__ hm, const float* __restrict__ Wr,
                    const float* __restrict__ br, float* __restrict__ wgt) {
  const int n = blockIdx.x;
  const int t = threadIdx.x;
  const int wid = t >> 6;
  const float4* row = (const float4*)(hm + (size_t)n * DDIM);
  float4 x[4];
#pragma unroll
  for (int j = 0; j < 4; ++j) x[j] = row[t + j * 256];
  __shared__ float red[KEXP][4];
  float part[KEXP];
#pragma unroll
  for (int k = 0; k < KEXP; ++k) {
    const float4* wr = (const float4*)(Wr + (size_t)k * DDIM);
    float s = 0.f;
#pragma unroll
    for (int j = 0; j < 4; ++j) {
      float4 w4 = wr[t + j * 256];
      s += x[j].x * w4.x + x[j].y * w4.y + x[j].z * w4.z + x[j].w * w4.w;
    }
#pragma unroll
    for (int off = 32; off > 0; off >>= 1) s += __shfl_down(s, off);
    part[k] = s;
  }
  if ((t & 63) == 0) {
#pragma unroll
    for (int k = 0; k < KEXP; ++k) red[k][wid] = part[k];
  }
  __syncthreads();
  if (t == 0) {
    float lg[KEXP];
    float mx = -1e30f;
#pragma unroll
    for (int k = 0; k < KEXP; ++k) {
      lg[k] = red[k][0] + red[k][1] + red[k][2] + red[k][3] + br[k];
      mx = fmaxf(mx, lg[k]);
    }
    float sum = 0.f;
#pragma unroll
    for (int k = 0; k < KEXP; ++k) { lg[k] = expf(lg[k] - mx); sum += lg[k]; }
    float inv = 1.f / sum;
#pragma unroll
    for (int k = 0; k < KEXP; ++k) wgt[(size_t)n * KEXP + k] = lg[k] * inv;
  }
}

// ---------------- conversions to bf16 ----------------
__device__ __forceinline__ bf16x8 cvt8(float4 f0, float4 f1) {
  bf16x8 o;
  o[0] = (bf16_t)f0.x; o[1] = (bf16_t)f0.y; o[2] = (bf16_t)f0.z; o[3] = (bf16_t)f0.w;
  o[4] = (bf16_t)f1.x; o[5] = (bf16_t)f1.y; o[6] = (bf16_t)f1.z; o[7] = (bf16_t)f1.w;
  return o;
}

// A[n][0:4096]=h_anchor, A[n][4096:8192]=h_mask   (concat, bf16)
__global__ __launch_bounds__(256)
void conv_cond_kernel(const float* __restrict__ ha, const float* __restrict__ hm,
                      bf16_t* __restrict__ A) {
  size_t c = (size_t)blockIdx.x * 256 + threadIdx.x;  // chunk of 8 elements
  int n   = (int)(c >> 10);                           // 1024 chunks per row of 8192
  int pos = ((int)c & 1023) * 8;
  const float* src = (pos < DDIM) ? ha + (size_t)n * DDIM + pos
                                  : hm + (size_t)n * DDIM + (pos - DDIM);
  float4 f0 = ((const float4*)src)[0];
  float4 f1 = ((const float4*)src)[1];
  *(bf16x8*)(A + c * 8) = cvt8(f0, f1);
}

// straight fp32 -> bf16 cast (W1: already [K*F][2D] row-major)
__global__ __launch_bounds__(256)
void conv_cast_kernel(const float* __restrict__ in, bf16_t* __restrict__ out) {
  size_t c = (size_t)blockIdx.x * 256 + threadIdx.x;
  float4 f0 = ((const float4*)(in + c * 8))[0];
  float4 f1 = ((const float4*)(in + c * 8))[1];
  *(bf16x8*)(out + c * 8) = cvt8(f0, f1);
}

// W2[k][d][f] -> B2[d][k*F+f]  (bf16)
__global__ __launch_bounds__(256)
void conv_w2_kernel(const float* __restrict__ W2, bf16_t* __restrict__ B2) {
  size_t c = (size_t)blockIdx.x * 256 + threadIdx.x;  // over K*D*F/8
  int f8 = (int)(c & 127);
  int d  = (int)((c >> 7) & 4095);
  int k  = (int)(c >> 19);
  const float* src = W2 + ((size_t)k * DDIM + d) * FHID + f8 * 8;
  float4 f0 = ((const float4*)src)[0];
  float4 f1 = ((const float4*)src)[1];
  *(bf16x8*)(B2 + (size_t)d * KD + k * FHID + f8 * 8) = cvt8(f0, f1);
}

// ---------------- 256x256 phase-split GEMM: C = A @ B^T over KD=8192 ----------------
// BK=32, 4-deep LDS pipeline (4 x 32KB buffers), 8 waves (2Mx4N).
// SINGLE barrier per K-tile + counted waitcnts:
//   vmcnt(8) ; s_barrier ; issue 4 gload_lds(t+3) + 12 ds_read(t) ;
//   lgkmcnt(4) ; 16 MFMA (Q0) ; lgkmcnt(0) ; 16 MFMA (Q1)
// Safety (rendezvous): every wave executes vmcnt(8) BEFORE barrier(t) -> at release,
// all waves' tile-t loads landed. Every wave passed lgkmcnt(0) for tile t-1 reads
// before reaching barrier(t) -> staging into buffer (t+3)&3 == (t-1)&3, issued after
// barrier(t), cannot overwrite live reads. Modular staging keeps exactly 12 loads
// in flight at every top-of-loop so vmcnt(8) retires precisely tile t's 4 loads.
// LDS swizzle (T2): involution  byte ^= ((byte>>7)&3)<<4  on BOTH sides (rule #21).
// Block-order remap: 16x16 output-tile windows, 4bm x 8bn per XCD, bijective.
// MODE 1: epilogue = +b1, exact GELU, *w[n][col>>10], store bf16 (H1s)
// MODE 2: epilogue = + sum_k w[n][k]*b2[k][col], store fp32 (out)
template <int MODE, int NCOLS>
__global__ __launch_bounds__(512, 2)
void gemm256_kernel(const bf16_t* __restrict__ Amat, const bf16_t* __restrict__ Bmat,
                    void* __restrict__ Cout, const float* __restrict__ bias,
                    const float* __restrict__ wgt) {
  constexpr int BM = 256, BN = 256, BK = 32;
  constexpr int NT = KD / BK;            // 256 K-tiles
  constexpr int BUFB = 32768;            // bytes per buffer (A 16KB + B 16KB)
  __shared__ char lds_raw[4 * BUFB];     // 128 KB

  const int tid  = threadIdx.x;
  const int wid  = tid >> 6;
  const int lane = tid & 63;
  const int wr   = wid >> 2;             // 0..1  (M half)
  const int wc   = wid & 3;              // 0..3  (N quarter)

  // ---- 2-D concurrency-window block remap (16x16 window, 4x8 per XCD)
  constexpr int NBN    = NCOLS / BN;     // 32 (GEMM1) or 16 (GEMM2)
  constexpr int NWIN_N = NBN / 16;       // 2 or 1
  const int bid = blockIdx.x;
  const int w   = bid >> 8;              // concurrency window index
  const int sl  = bid & 255;
  const int xcd = sl & 7;
  const int cu  = sl >> 3;               // 0..31 within XCD
  const int wm  = w / NWIN_N, wn = w % NWIN_N;
  const int bm  = wm * 16 + ((xcd >> 1) << 2) + (cu & 3);
  const int bn  = wn * 16 + ((xcd & 1) << 3) + (cu >> 2);
  const int arow0 = bm * BM;
  const int brow0 = bn * BN;

  // ---- staging descriptors: per-thread global src (inverse-swizzled), uniform LDS dst
  const bf16_t* srcA[2];
  const bf16_t* srcB[2];
  int dstA[2], dstB[2];
#pragma unroll
  for (int i = 0; i < 2; ++i) {
    int p    = i * 8192 + tid * 16;                 // phys byte within region
    int l    = p ^ (((p >> 7) & 3) << 4);           // logical byte (involution)
    int lrow = l >> 6;
    int lcol = (l & 63) >> 1;
    srcA[i] = Amat + (size_t)(arow0 + lrow) * KD + lcol;
    srcB[i] = Bmat + (size_t)(brow0 + lrow) * KD + lcol;
    dstA[i] = i * 8192 + (wid << 10);               // wave-uniform (no lane part)
    dstB[i] = 16384 + dstA[i];
  }

  // ---- ds_read byte offsets (swizzled)
  const int j = lane >> 4;
  int aoffB[8], boffB[4];
#pragma unroll
  for (int mi = 0; mi < 8; ++mi) {
    int row = wr * 128 + mi * 16 + (lane & 15);
    aoffB[mi] = row * 64 + ((j ^ ((row >> 1) & 3)) << 4);
  }
#pragma unroll
  for (int ni = 0; ni < 4; ++ni) {
    int row = wc * 64 + ni * 16 + (lane & 15);
    boffB[ni] = 16384 + row * 64 + ((j ^ ((row >> 1) & 3)) << 4);
  }

  f32x4 acc[8][4];
  f32x4 zero = {0.f, 0.f, 0.f, 0.f};
#pragma unroll
  for (int mi = 0; mi < 8; ++mi)
#pragma unroll
    for (int ni = 0; ni < 4; ++ni) acc[mi][ni] = zero;

  // ---- prologue: stage tiles 0..2 into buffers 0..2 (A0,A1,B0,B1 each)
#pragma unroll
  for (int pt = 0; pt < 3; ++pt) {
    char* base = lds_raw + pt * BUFB;
#pragma unroll
    for (int i = 0; i < 2; ++i) gload_lds16(srcA[i] + (size_t)pt * BK, base + dstA[i]);
#pragma unroll
    for (int i = 0; i < 2; ++i) gload_lds16(srcB[i] + (size_t)pt * BK, base + dstB[i]);
  }

  // ---- main loop: one barrier per tile, counted lgkm overlap of Q1-reads under Q0-MFMA
  for (int t = 0; t < NT; ++t) {
    const int bufo = (t & 3) * BUFB;
    const int ts   = (t + 3) & (NT - 1);            // modular staging tile
    char* sbase = lds_raw + ((t + 3) & 3) * BUFB;

    asm volatile("s_waitcnt vmcnt(8)" ::: "memory");  // tile t landed (t+1,t+2 in flight)
    __builtin_amdgcn_s_barrier();

    // issue staging for t+3 (4 x global_load_lds), then all 12 ds_reads of tile t
#pragma unroll
    for (int i = 0; i < 2; ++i) gload_lds16(srcA[i] + (size_t)ts * BK, sbase + dstA[i]);
#pragma unroll
    for (int i = 0; i < 2; ++i) gload_lds16(srcB[i] + (size_t)ts * BK, sbase + dstB[i]);

    bf16x8 a0[4], bb[4], a1[4];
#pragma unroll
    for (int mi = 0; mi < 4; ++mi)
      a0[mi] = *(const bf16x8*)(lds_raw + bufo + aoffB[mi]);
#pragma unroll
    for (int ni = 0; ni < 4; ++ni)
      bb[ni] = *(const bf16x8*)(lds_raw + bufo + boffB[ni]);
    __builtin_amdgcn_sched_barrier(0);              // pin: Q0's 8 reads issued first
#pragma unroll
    for (int mi = 0; mi < 4; ++mi)
      a1[mi] = *(const bf16x8*)(lds_raw + bufo + aoffB[mi + 4]);
    __builtin_amdgcn_sched_barrier(0);

    asm volatile("s_waitcnt lgkmcnt(4)" ::: "memory");  // Q0's 8 retired (a1's 4 in flight)
    __builtin_amdgcn_sched_barrier(0);
    __builtin_amdgcn_s_setprio(1);
#pragma unroll
    for (int mi = 0; mi < 4; ++mi)
#pragma unroll
      for (int ni = 0; ni < 4; ++ni)
        acc[mi][ni] = __builtin_amdgcn_mfma_f32_16x16x32_bf16(a0[mi], bb[ni], acc[mi][ni], 0, 0, 0);
    __builtin_amdgcn_s_setprio(0);
    __builtin_amdgcn_sched_barrier(0);

    asm volatile("s_waitcnt lgkmcnt(0)" ::: "memory");  // a1 retired (drained under Q0 MFMA)
    __builtin_amdgcn_sched_barrier(0);
    __builtin_amdgcn_s_setprio(1);
#pragma unroll
    for (int mi = 0; mi < 4; ++mi)
#pragma unroll
      for (int ni = 0; ni < 4; ++ni)
        acc[mi + 4][ni] = __builtin_amdgcn_mfma_f32_16x16x32_bf16(a1[mi], bb[ni], acc[mi + 4][ni], 0, 0, 0);
    __builtin_amdgcn_s_setprio(0);
    __builtin_amdgcn_sched_barrier(0);
  }

  // ---- epilogue.  C/D layout: row = (lane>>4)*4 + r, col = lane&15  [m89/m91]
  const int grow0 = arow0 + wr * 128 + ((lane >> 4) << 2);
  const int gcol0 = brow0 + wc * 64 + (lane & 15);

  if constexpr (MODE == 1) {
    bf16_t* __restrict__ H = (bf16_t*)Cout;
    const int kexp = brow0 >> 10;  // expert is block-uniform (256 | 1024)
#pragma unroll
    for (int mi = 0; mi < 8; ++mi) {
      float wn4[4];
#pragma unroll
      for (int r = 0; r < 4; ++r)
        wn4[r] = wgt[(size_t)(grow0 + mi * 16 + r) * KEXP + kexp];
#pragma unroll
      for (int ni = 0; ni < 4; ++ni) {
        int col = gcol0 + ni * 16;
        float bv = bias[col];
#pragma unroll
        for (int r = 0; r < 4; ++r) {
          int n = grow0 + mi * 16 + r;
          float x = acc[mi][ni][r] + bv;
          float g = 0.5f * x * (1.f + erff(x * 0.70710678118654752f));  // exact GELU
          H[(size_t)n * KD + col] = (bf16_t)(g * wn4[r]);
        }
      }
    }
  } else {
    float* __restrict__ O = (float*)Cout;
    float bcol[4][KEXP];
#pragma unroll
    for (int ni = 0; ni < 4; ++ni)
#pragma unroll
      for (int k = 0; k < KEXP; ++k)
        bcol[ni][k] = bias[(size_t)k * NCOLS + gcol0 + ni * 16];
#pragma unroll
    for (int mi = 0; mi < 8; ++mi)
#pragma unroll
      for (int r = 0; r < 4; ++r) {
        int n = grow0 + mi * 16 + r;
        const float4* wp = (const float4*)(wgt + (size_t)n * KEXP);
        float4 wa = wp[0], wb = wp[1];
        float w8[KEXP] = {wa.x, wa.y, wa.z, wa.w, wb.x, wb.y, wb.z, wb.w};
#pragma unroll
        for (int ni = 0; ni < 4; ++ni) {
          float bb2 = 0.f;
#pragma unroll
          for (int k = 0; k < KEXP; ++k) bb2 += w8[k] * bcol[ni][k];
          O[(size_t)n * NCOLS + gcol0 + ni * 16] = acc[mi][ni][r] + bb2;
        }
      }
  }
}

extern "C" void kernel_launch(void* const* d_in, const int* in_sizes, int n_in,
                              void* d_out, int out_size, void* d_ws, size_t ws_size,
                              hipStream_t stream) {
  const float* h_anchor = (const float*)d_in[0];
  const float* h_mask   = (const float*)d_in[1];
  const float* Wr       = (const float*)d_in[2];
  const float* br       = (const float*)d_in[3];
  const float* W1       = (const float*)d_in[4];
  const float* b1       = (const float*)d_in[5];
  const float* W2       = (const float*)d_in[6];
  const float* b2       = (const float*)d_in[7];
  float* out = (float*)d_out;

  char* ws = (char*)d_ws;
  bf16_t* Abf  = (bf16_t*)(ws);                       // [8192][8192] bf16 = 128 MB
  bf16_t* W1bf = (bf16_t*)(ws + ((size_t)128 << 20)); // [8192][8192] bf16 = 128 MB
  bf16_t* W2bf = (bf16_t*)(ws + ((size_t)256 << 20)); // [4096][8192] bf16 =  64 MB
  bf16_t* H1s  = (bf16_t*)(ws + ((size_t)320 << 20)); // [8192][8192] bf16 = 128 MB
  float*  wgt  = (float*) (ws + ((size_t)448 << 20)); // [8192][8]   fp32 = 256 KB

  routing_kernel<<<N_ROWS, 256, 0, stream>>>(h_mask, Wr, br, wgt);
  conv_cond_kernel<<<(N_ROWS * KD / 8) / 256, 256, 0, stream>>>(h_anchor, h_mask, Abf);
  conv_cast_kernel<<<(KEXP * FHID * 2 * DDIM / 8) / 256, 256, 0, stream>>>(W1, W1bf);
  conv_w2_kernel<<<(KEXP * DDIM * FHID / 8) / 256, 256, 0, stream>>>(W2, W2bf);

  gemm256_kernel<1, 8192><<<(N_ROWS / 256) * (KD / 256), 512, 0, stream>>>(
      Abf, W1bf, (void*)H1s, b1, wgt);
  gemm256_kernel<2, 4096><<<(N_ROWS / 256) * (DDIM / 256), 512, 0, stream>>>(
      H1s, W2bf, (void*)out, b2, wgt);
}

// Round 6
// 1598.454 us; speedup vs baseline: 1.5736x; 1.0265x over previous
//
#include <hip/hip_runtime.h>
#include <hip/hip_bf16.h>
#include <math.h>

typedef __bf16 bf16_t;
typedef __bf16 bf16x8 __attribute__((ext_vector_type(8)));
typedef float  f32x4  __attribute__((ext_vector_type(4)));

#define AS1 __attribute__((address_space(1)))
#define AS3 __attribute__((address_space(3)))

__device__ __forceinline__ void gload_lds16(const bf16_t* g, char* l) {
  __builtin_amdgcn_global_load_lds((const AS1 void*)g, (AS3 void*)l, 16, 0, 0);
}

static constexpr int N_ROWS = 8192;
static constexpr int DDIM   = 4096;
static constexpr int KEXP   = 8;
static constexpr int FHID   = 1024;
static constexpr int KD     = 8192;   // inner dim of both GEMMs (2D and K*F)

// ---------------- routing: weights = softmax(h_mask @ Wr^T + br) ----------------
__global__ __launch_bounds__(256)
void routing_kernel(const float* __restrict__ hm, const float* __restrict__ Wr,
                    const float* __restrict__ br, float* __restrict__ wgt) {
  const int n = blockIdx.x;
  const int t = threadIdx.x;
  const int wid = t >> 6;
  const float4* row = (const float4*)(hm + (size_t)n * DDIM);
  float4 x[4];
#pragma unroll
  for (int j = 0; j < 4; ++j) x[j] = row[t + j * 256];
  __shared__ float red[KEXP][4];
  float part[KEXP];
#pragma unroll
  for (int k = 0; k < KEXP; ++k) {
    const float4* wr = (const float4*)(Wr + (size_t)k * DDIM);
    float s = 0.f;
#pragma unroll
    for (int j = 0; j < 4; ++j) {
      float4 w4 = wr[t + j * 256];
      s += x[j].x * w4.x + x[j].y * w4.y + x[j].z * w4.z + x[j].w * w4.w;
    }
#pragma unroll
    for (int off = 32; off > 0; off >>= 1) s += __shfl_down(s, off);
    part[k] = s;
  }
  if ((t & 63) == 0) {
#pragma unroll
    for (int k = 0; k < KEXP; ++k) red[k][wid] = part[k];
  }
  __syncthreads();
  if (t == 0) {
    float lg[KEXP];
    float mx = -1e30f;
#pragma unroll
    for (int k = 0; k < KEXP; ++k) {
      lg[k] = red[k][0] + red[k][1] + red[k][2] + red[k][3] + br[k];
      mx = fmaxf(mx, lg[k]);
    }
    float sum = 0.f;
#pragma unroll
    for (int k = 0; k < KEXP; ++k) { lg[k] = expf(lg[k] - mx); sum += lg[k]; }
    float inv = 1.f / sum;
#pragma unroll
    for (int k = 0; k < KEXP; ++k) wgt[(size_t)n * KEXP + k] = lg[k] * inv;
  }
}

// ---------------- conversions to bf16 ----------------
__device__ __forceinline__ bf16x8 cvt8(float4 f0, float4 f1) {
  bf16x8 o;
  o[0] = (bf16_t)f0.x; o[1] = (bf16_t)f0.y; o[2] = (bf16_t)f0.z; o[3] = (bf16_t)f0.w;
  o[4] = (bf16_t)f1.x; o[5] = (bf16_t)f1.y; o[6] = (bf16_t)f1.z; o[7] = (bf16_t)f1.w;
  return o;
}

// A[n][0:4096]=h_anchor, A[n][4096:8192]=h_mask   (concat, bf16)
__global__ __launch_bounds__(256)
void conv_cond_kernel(const float* __restrict__ ha, const float* __restrict__ hm,
                      bf16_t* __restrict__ A) {
  size_t c = (size_t)blockIdx.x * 256 + threadIdx.x;  // chunk of 8 elements
  int n   = (int)(c >> 10);                           // 1024 chunks per row of 8192
  int pos = ((int)c & 1023) * 8;
  const float* src = (pos < DDIM) ? ha + (size_t)n * DDIM + pos
                                  : hm + (size_t)n * DDIM + (pos - DDIM);
  float4 f0 = ((const float4*)src)[0];
  float4 f1 = ((const float4*)src)[1];
  *(bf16x8*)(A + c * 8) = cvt8(f0, f1);
}

// straight fp32 -> bf16 cast (W1: already [K*F][2D] row-major)
__global__ __launch_bounds__(256)
void conv_cast_kernel(const float* __restrict__ in, bf16_t* __restrict__ out) {
  size_t c = (size_t)blockIdx.x * 256 + threadIdx.x;
  float4 f0 = ((const float4*)(in + c * 8))[0];
  float4 f1 = ((const float4*)(in + c * 8))[1];
  *(bf16x8*)(out + c * 8) = cvt8(f0, f1);
}

// W2[k][d][f] -> B2[d][k*F+f]  (bf16)
__global__ __launch_bounds__(256)
void conv_w2_kernel(const float* __restrict__ W2, bf16_t* __restrict__ B2) {
  size_t c = (size_t)blockIdx.x * 256 + threadIdx.x;  // over K*D*F/8
  int f8 = (int)(c & 127);
  int d  = (int)((c >> 7) & 4095);
  int k  = (int)(c >> 19);
  const float* src = W2 + ((size_t)k * DDIM + d) * FHID + f8 * 8;
  float4 f0 = ((const float4*)src)[0];
  float4 f1 = ((const float4*)src)[1];
  *(bf16x8*)(B2 + (size_t)d * KD + k * FHID + f8 * 8) = cvt8(f0, f1);
}

// ---------------- 256x256 register-prefetch GEMM: C = A @ B^T over KD=8192 ----------------
// BK=32, 4-deep LDS ring (4 x 32KB), 8 waves (2Mx4N), 1 barrier/tile.
// REGISTER PREFETCH: ds_reads for tile t+1 issue DURING tile t's MFMA (vmcnt(4) at top
// of body t already guarantees tile t+1 is in LDS). Rolling frag lifetime, peak ~16
// frags. FIFO ds retirement + pinned issue order makes each lgkmcnt(4) exact:
//   top:  vmcnt(4); barrier; gloads(t+3);
//         lgkm(4) [a0,bb ready, a1 in flight] ; Q0-MFMA ; issue a0'(t+1)
//         lgkm(4) [a1 ready, a0' in flight]   ; Q1-MFMA ; issue bb'(t+1); a1'(t+1)
// Buffer safety: in-flight reads always target (t+1)&3; gloads target (t+3)&3 (disjoint,
// differ by 2 mod 4); reads of a buffer retire a full body before it is re-staged.
// Modular staging keeps vmcnt counts uniform (incl. tail; round-3 lesson).
// LDS swizzle (T2): involution  byte ^= ((byte>>7)&3)<<4  on BOTH sides (rule #21).
// Block-order remap: 16x16 output-tile windows, 4bm x 8bn per XCD, bijective.
// MODE 1: epilogue = +b1, exact GELU, *w[n][col>>10], store bf16 (H1s)
// MODE 2: epilogue = + sum_k w[n][k]*b2[k][col], store fp32 (out)
template <int MODE, int NCOLS>
__global__ __launch_bounds__(512, 2)
void gemm256_kernel(const bf16_t* __restrict__ Amat, const bf16_t* __restrict__ Bmat,
                    void* __restrict__ Cout, const float* __restrict__ bias,
                    const float* __restrict__ wgt) {
  constexpr int BM = 256, BN = 256, BK = 32;
  constexpr int NT = KD / BK;            // 256 K-tiles
  constexpr int BUFB = 32768;            // bytes per buffer (A 16KB + B 16KB)
  __shared__ char lds_raw[4 * BUFB];     // 128 KB

  const int tid  = threadIdx.x;
  const int wid  = tid >> 6;
  const int lane = tid & 63;
  const int wr   = wid >> 2;             // 0..1  (M half)
  const int wc   = wid & 3;              // 0..3  (N quarter)

  // ---- 2-D concurrency-window block remap (16x16 window, 4x8 per XCD)
  constexpr int NBN    = NCOLS / BN;     // 32 (GEMM1) or 16 (GEMM2)
  constexpr int NWIN_N = NBN / 16;       // 2 or 1
  const int bid = blockIdx.x;
  const int w   = bid >> 8;              // concurrency window index
  const int sl  = bid & 255;
  const int xcd = sl & 7;
  const int cu  = sl >> 3;               // 0..31 within XCD
  const int wm  = w / NWIN_N, wn = w % NWIN_N;
  const int bm  = wm * 16 + ((xcd >> 1) << 2) + (cu & 3);
  const int bn  = wn * 16 + ((xcd & 1) << 3) + (cu >> 2);
  const int arow0 = bm * BM;
  const int brow0 = bn * BN;

  // ---- staging descriptors: per-thread global src (inverse-swizzled), uniform LDS dst
  const bf16_t* srcA[2];
  const bf16_t* srcB[2];
  int dstA[2], dstB[2];
#pragma unroll
  for (int i = 0; i < 2; ++i) {
    int p    = i * 8192 + tid * 16;                 // phys byte within region
    int l    = p ^ (((p >> 7) & 3) << 4);           // logical byte (involution)
    int lrow = l >> 6;
    int lcol = (l & 63) >> 1;
    srcA[i] = Amat + (size_t)(arow0 + lrow) * KD + lcol;
    srcB[i] = Bmat + (size_t)(brow0 + lrow) * KD + lcol;
    dstA[i] = i * 8192 + (wid << 10);               // wave-uniform (no lane part)
    dstB[i] = 16384 + dstA[i];
  }

  // ---- ds_read byte offsets (swizzled)
  const int j = lane >> 4;
  int aoffB[8], boffB[4];
#pragma unroll
  for (int mi = 0; mi < 8; ++mi) {
    int row = wr * 128 + mi * 16 + (lane & 15);
    aoffB[mi] = row * 64 + ((j ^ ((row >> 1) & 3)) << 4);
  }
#pragma unroll
  for (int ni = 0; ni < 4; ++ni) {
    int row = wc * 64 + ni * 16 + (lane & 15);
    boffB[ni] = 16384 + row * 64 + ((j ^ ((row >> 1) & 3)) << 4);
  }

  f32x4 acc[8][4];
  f32x4 zero = {0.f, 0.f, 0.f, 0.f};
#pragma unroll
  for (int mi = 0; mi < 8; ++mi)
#pragma unroll
    for (int ni = 0; ni < 4; ++ni) acc[mi][ni] = zero;

  // ---- prologue: stage tiles 0..2 into buffers 0..2
#pragma unroll
  for (int pt = 0; pt < 3; ++pt) {
    char* base = lds_raw + pt * BUFB;
#pragma unroll
    for (int i = 0; i < 2; ++i) gload_lds16(srcA[i] + (size_t)pt * BK, base + dstA[i]);
#pragma unroll
    for (int i = 0; i < 2; ++i) gload_lds16(srcB[i] + (size_t)pt * BK, base + dstB[i]);
  }

  // two named fragment sets (rule #20: no runtime-indexed frag arrays)
  bf16x8 a0X[4], bbX[4], a1X[4];
  bf16x8 a0Y[4], bbY[4], a1Y[4];

  // prologue frag reads for tile 0 into X (issue order a0, bb, a1 — pinned)
  asm volatile("s_waitcnt vmcnt(8)" ::: "memory");   // tile 0 landed
  __builtin_amdgcn_s_barrier();
#pragma unroll
  for (int mi = 0; mi < 4; ++mi) a0X[mi] = *(const bf16x8*)(lds_raw + aoffB[mi]);
  __builtin_amdgcn_sched_barrier(0);
#pragma unroll
  for (int ni = 0; ni < 4; ++ni) bbX[ni] = *(const bf16x8*)(lds_raw + boffB[ni]);
  __builtin_amdgcn_sched_barrier(0);
#pragma unroll
  for (int mi = 0; mi < 4; ++mi) a1X[mi] = *(const bf16x8*)(lds_raw + aoffB[mi + 4]);
  __builtin_amdgcn_sched_barrier(0);

#define GBODY(T, A0C, BBC, A1C, A0N, BBN, A1N)                                          \
  {                                                                                     \
    const int ts   = ((T) + 3) & (NT - 1);                                              \
    char* sbase = lds_raw + (((T) + 3) & 3) * BUFB;                                     \
    char* nbase = lds_raw + (((T) + 1) & 3) * BUFB;                                     \
    asm volatile("s_waitcnt vmcnt(4)" ::: "memory"); /* tile T+1 landed */              \
    __builtin_amdgcn_s_barrier();                                                       \
    _Pragma("unroll")                                                                   \
    for (int i = 0; i < 2; ++i) gload_lds16(srcA[i] + (size_t)ts * BK, sbase + dstA[i]);\
    _Pragma("unroll")                                                                   \
    for (int i = 0; i < 2; ++i) gload_lds16(srcB[i] + (size_t)ts * BK, sbase + dstB[i]);\
    __builtin_amdgcn_sched_barrier(0);                                                  \
    asm volatile("s_waitcnt lgkmcnt(4)" ::: "memory"); /* A0C,BBC ready */              \
    __builtin_amdgcn_sched_barrier(0);                                                  \
    __builtin_amdgcn_s_setprio(1);                                                      \
    _Pragma("unroll")                                                                   \
    for (int mi = 0; mi < 4; ++mi)                                                      \
      _Pragma("unroll")                                                                 \
      for (int ni = 0; ni < 4; ++ni)                                                    \
        acc[mi][ni] = __builtin_amdgcn_mfma_f32_16x16x32_bf16(A0C[mi], BBC[ni],         \
                                                              acc[mi][ni], 0, 0, 0);    \
    __builtin_amdgcn_s_setprio(0);                                                      \
    __builtin_amdgcn_sched_barrier(0);                                                  \
    _Pragma("unroll")                                                                   \
    for (int mi = 0; mi < 4; ++mi) A0N[mi] = *(const bf16x8*)(nbase + aoffB[mi]);       \
    __builtin_amdgcn_sched_barrier(0);                                                  \
    asm volatile("s_waitcnt lgkmcnt(4)" ::: "memory"); /* A1C ready */                  \
    __builtin_amdgcn_sched_barrier(0);                                                  \
    __builtin_amdgcn_s_setprio(1);                                                      \
    _Pragma("unroll")                                                                   \
    for (int mi = 0; mi < 4; ++mi)                                                      \
      _Pragma("unroll")                                                                 \
      for (int ni = 0; ni < 4; ++ni)                                                    \
        acc[mi + 4][ni] = __builtin_amdgcn_mfma_f32_16x16x32_bf16(A1C[mi], BBC[ni],     \
                                                                 acc[mi + 4][ni],       \
                                                                 0, 0, 0);              \
    __builtin_amdgcn_s_setprio(0);                                                      \
    __builtin_amdgcn_sched_barrier(0);                                                  \
    _Pragma("unroll")                                                                   \
    for (int ni = 0; ni < 4; ++ni) BBN[ni] = *(const bf16x8*)(nbase + boffB[ni]);       \
    __builtin_amdgcn_sched_barrier(0);                                                  \
    _Pragma("unroll")                                                                   \
    for (int mi = 0; mi < 4; ++mi) A1N[mi] = *(const bf16x8*)(nbase + aoffB[mi + 4]);   \
    __builtin_amdgcn_sched_barrier(0);                                                  \
  }

  for (int t = 0; t < NT; t += 2) {
    GBODY(t,     a0X, bbX, a1X, a0Y, bbY, a1Y);
    GBODY(t + 1, a0Y, bbY, a1Y, a0X, bbX, a1X);
  }
#undef GBODY

  // ---- epilogue.  C/D layout: row = (lane>>4)*4 + r, col = lane&15  [m89/m91]
  const int grow0 = arow0 + wr * 128 + ((lane >> 4) << 2);
  const int gcol0 = brow0 + wc * 64 + (lane & 15);

  if constexpr (MODE == 1) {
    bf16_t* __restrict__ H = (bf16_t*)Cout;
    const int kexp = brow0 >> 10;  // expert is block-uniform (256 | 1024)
#pragma unroll
    for (int mi = 0; mi < 8; ++mi) {
      float wn4[4];
#pragma unroll
      for (int r = 0; r < 4; ++r)
        wn4[r] = wgt[(size_t)(grow0 + mi * 16 + r) * KEXP + kexp];
#pragma unroll
      for (int ni = 0; ni < 4; ++ni) {
        int col = gcol0 + ni * 16;
        float bv = bias[col];
#pragma unroll
        for (int r = 0; r < 4; ++r) {
          int n = grow0 + mi * 16 + r;
          float x = acc[mi][ni][r] + bv;
          float g = 0.5f * x * (1.f + erff(x * 0.70710678118654752f));  // exact GELU
          H[(size_t)n * KD + col] = (bf16_t)(g * wn4[r]);
        }
      }
    }
  } else {
    float* __restrict__ O = (float*)Cout;
    float bcol[4][KEXP];
#pragma unroll
    for (int ni = 0; ni < 4; ++ni)
#pragma unroll
      for (int k = 0; k < KEXP; ++k)
        bcol[ni][k] = bias[(size_t)k * NCOLS + gcol0 + ni * 16];
#pragma unroll
    for (int mi = 0; mi < 8; ++mi)
#pragma unroll
      for (int r = 0; r < 4; ++r) {
        int n = grow0 + mi * 16 + r;
        const float4* wp = (const float4*)(wgt + (size_t)n * KEXP);
        float4 wa = wp[0], wb = wp[1];
        float w8[KEXP] = {wa.x, wa.y, wa.z, wa.w, wb.x, wb.y, wb.z, wb.w};
#pragma unroll
        for (int ni = 0; ni < 4; ++ni) {
          float bb2 = 0.f;
#pragma unroll
          for (int k = 0; k < KEXP; ++k) bb2 += w8[k] * bcol[ni][k];
          O[(size_t)n * NCOLS + gcol0 + ni * 16] = acc[mi][ni][r] + bb2;
        }
      }
  }
}

extern "C" void kernel_launch(void* const* d_in, const int* in_sizes, int n_in,
                              void* d_out, int out_size, void* d_ws, size_t ws_size,
                              hipStream_t stream) {
  const float* h_anchor = (const float*)d_in[0];
  const float* h_mask   = (const float*)d_in[1];
  const float* Wr       = (const float*)d_in[2];
  const float* br       = (const float*)d_in[3];
  const float* W1       = (const float*)d_in[4];
  const float* b1       = (const float*)d_in[5];
  const float* W2       = (const float*)d_in[6];
  const float* b2       = (const float*)d_in[7];
  float* out = (float*)d_out;

  char* ws = (char*)d_ws;
  bf16_t* Abf  = (bf16_t*)(ws);                       // [8192][8192] bf16 = 128 MB
  bf16_t* W1bf = (bf16_t*)(ws + ((size_t)128 << 20)); // [8192][8192] bf16 = 128 MB
  bf16_t* W2bf = (bf16_t*)(ws + ((size_t)256 << 20)); // [4096][8192] bf16 =  64 MB
  bf16_t* H1s  = (bf16_t*)(ws + ((size_t)320 << 20)); // [8192][8192] bf16 = 128 MB
  float*  wgt  = (float*) (ws + ((size_t)448 << 20)); // [8192][8]   fp32 = 256 KB

  routing_kernel<<<N_ROWS, 256, 0, stream>>>(h_mask, Wr, br, wgt);
  conv_cond_kernel<<<(N_ROWS * KD / 8) / 256, 256, 0, stream>>>(h_anchor, h_mask, Abf);
  conv_cast_kernel<<<(KEXP * FHID * 2 * DDIM / 8) / 256, 256, 0, stream>>>(W1, W1bf);
  conv_w2_kernel<<<(KEXP * DDIM * FHID / 8) / 256, 256, 0, stream>>>(W2, W2bf);

  gemm256_kernel<1, 8192><<<(N_ROWS / 256) * (KD / 256), 512, 0, stream>>>(
      Abf, W1bf, (void*)H1s, b1, wgt);
  gemm256_kernel<2, 4096><<<(N_ROWS / 256) * (DDIM / 256), 512, 0, stream>>>(
      H1s, W2bf, (void*)out, b2, wgt);
}

// Round 7
// 1534.000 us; speedup vs baseline: 1.6397x; 1.0420x over previous
//
#include <hip/hip_runtime.h>
#include <hip/hip_bf16.h>
#include <math.h>

typedef __bf16 bf16_t;
typedef __bf16 bf16x8 __attribute__((ext_vector_type(8)));
typedef float  f32x4  __attribute__((ext_vector_type(4)));

#define AS1 __attribute__((address_space(1)))
#define AS3 __attribute__((address_space(3)))

__device__ __forceinline__ void gload_lds16(const bf16_t* g, char* l) {
  __builtin_amdgcn_global_load_lds((const AS1 void*)g, (AS3 void*)l, 16, 0, 0);
}

static constexpr int N_ROWS = 8192;
static constexpr int DDIM   = 4096;
static constexpr int KEXP   = 8;
static constexpr int FHID   = 1024;
static constexpr int KD     = 8192;   // inner dim of both GEMMs (2D and K*F)

// ---------------- routing: weights = softmax(h_mask @ Wr^T + br) ----------------
__global__ __launch_bounds__(256)
void routing_kernel(const float* __restrict__ hm, const float* __restrict__ Wr,
                    const float* __restrict__ br, float* __restrict__ wgt) {
  const int n = blockIdx.x;
  const int t = threadIdx.x;
  const int wid = t >> 6;
  const float4* row = (const float4*)(hm + (size_t)n * DDIM);
  float4 x[4];
#pragma unroll
  for (int j = 0; j < 4; ++j) x[j] = row[t + j * 256];
  __shared__ float red[KEXP][4];
  float part[KEXP];
#pragma unroll
  for (int k = 0; k < KEXP; ++k) {
    const float4* wr = (const float4*)(Wr + (size_t)k * DDIM);
    float s = 0.f;
#pragma unroll
    for (int j = 0; j < 4; ++j) {
      float4 w4 = wr[t + j * 256];
      s += x[j].x * w4.x + x[j].y * w4.y + x[j].z * w4.z + x[j].w * w4.w;
    }
#pragma unroll
    for (int off = 32; off > 0; off >>= 1) s += __shfl_down(s, off);
    part[k] = s;
  }
  if ((t & 63) == 0) {
#pragma unroll
    for (int k = 0; k < KEXP; ++k) red[k][wid] = part[k];
  }
  __syncthreads();
  if (t == 0) {
    float lg[KEXP];
    float mx = -1e30f;
#pragma unroll
    for (int k = 0; k < KEXP; ++k) {
      lg[k] = red[k][0] + red[k][1] + red[k][2] + red[k][3] + br[k];
      mx = fmaxf(mx, lg[k]);
    }
    float sum = 0.f;
#pragma unroll
    for (int k = 0; k < KEXP; ++k) { lg[k] = expf(lg[k] - mx); sum += lg[k]; }
    float inv = 1.f / sum;
#pragma unroll
    for (int k = 0; k < KEXP; ++k) wgt[(size_t)n * KEXP + k] = lg[k] * inv;
  }
}

// ---------------- conversions to bf16 ----------------
__device__ __forceinline__ bf16x8 cvt8(float4 f0, float4 f1) {
  bf16x8 o;
  o[0] = (bf16_t)f0.x; o[1] = (bf16_t)f0.y; o[2] = (bf16_t)f0.z; o[3] = (bf16_t)f0.w;
  o[4] = (bf16_t)f1.x; o[5] = (bf16_t)f1.y; o[6] = (bf16_t)f1.z; o[7] = (bf16_t)f1.w;
  return o;
}

// A[n][0:4096]=h_anchor, A[n][4096:8192]=h_mask   (concat, bf16)
__global__ __launch_bounds__(256)
void conv_cond_kernel(const float* __restrict__ ha, const float* __restrict__ hm,
                      bf16_t* __restrict__ A) {
  size_t c = (size_t)blockIdx.x * 256 + threadIdx.x;  // chunk of 8 elements
  int n   = (int)(c >> 10);                           // 1024 chunks per row of 8192
  int pos = ((int)c & 1023) * 8;
  const float* src = (pos < DDIM) ? ha + (size_t)n * DDIM + pos
                                  : hm + (size_t)n * DDIM + (pos - DDIM);
  float4 f0 = ((const float4*)src)[0];
  float4 f1 = ((const float4*)src)[1];
  *(bf16x8*)(A + c * 8) = cvt8(f0, f1);
}

// straight fp32 -> bf16 cast (W1: already [K*F][2D] row-major)
__global__ __launch_bounds__(256)
void conv_cast_kernel(const float* __restrict__ in, bf16_t* __restrict__ out) {
  size_t c = (size_t)blockIdx.x * 256 + threadIdx.x;
  float4 f0 = ((const float4*)(in + c * 8))[0];
  float4 f1 = ((const float4*)(in + c * 8))[1];
  *(bf16x8*)(out + c * 8) = cvt8(f0, f1);
}

// W2[k][d][f] -> B2[d][k*F+f]  (bf16)
__global__ __launch_bounds__(256)
void conv_w2_kernel(const float* __restrict__ W2, bf16_t* __restrict__ B2) {
  size_t c = (size_t)blockIdx.x * 256 + threadIdx.x;  // over K*D*F/8
  int f8 = (int)(c & 127);
  int d  = (int)((c >> 7) & 4095);
  int k  = (int)(c >> 19);
  const float* src = W2 + ((size_t)k * DDIM + d) * FHID + f8 * 8;
  float4 f0 = ((const float4*)src)[0];
  float4 f1 = ((const float4*)src)[1];
  *(bf16x8*)(B2 + (size_t)d * KD + k * FHID + f8 * 8) = cvt8(f0, f1);
}

// ---------------- 256x256 8-phase GEMM (m201-template port): C = A @ B^T, K=8192 ----
// BK=64, 2 LDS buffers (64 KB each: A 32K + B 32K), 8 waves (2Mx4N), 512 thr.
// Body = 2 K-tiles (t even->buf0 phases 0-3, t+1->buf1 phases 4-7).
// Phase (h,s): {4-8 ds_read_b128 -> stage 1 half (2 gloads) -> barrier -> lgkm(0) ->
//               setprio(1) 16 MFMA setprio(0) -> [gate vmcnt(2)] -> barrier}
// Stage rotation (slot -> half): A0(t+1), A1(t+1), B1(t+1), B0(t+2)+gate,
//                                A0(t+2), A1(t+2), B1(t+2), B0(t+3)+gate.
// Safety audit: B halves of a buffer are last read in phase (h0,s1) (2 of 4) ->
// freed at that phase's end barrier -> B stages land >=1 phase later. A halves
// read through phase (h1,s1) -> A stages issue the following phase. vmcnt(2) at
// gates guarantees every half lands before first consumption (all but the
// newest half retired). Modular tile wrap keeps counts uniform (round-3 lesson).
// LDS swizzle: involution p ^= ((p>>7)&3)<<4 ^ ((p>>9)&1)<<6 (128B rows) -> 2-way
// bank access (free); applied inverse-on-global-source + forward-on-ds_read (#21).
// ONE live fragment set (aq[4]+bb[4]) - low VGPR pressure (r6 lesson: dual-set
// prefetch caused AGPR shuttling, VALUBusy 30%).
// MODE 1: epilogue = +b1, exact GELU, *w[n][col>>10], store bf16 (H1s)
// MODE 2: epilogue = + sum_k w[n][k]*b2[k][col], store fp32 (out)
template <int MODE, int NCOLS>
__global__ __launch_bounds__(512, 2)
void gemm256_kernel(const bf16_t* __restrict__ Amat, const bf16_t* __restrict__ Bmat,
                    void* __restrict__ Cout, const float* __restrict__ bias,
                    const float* __restrict__ wgt) {
  constexpr int BM = 256, BN = 256, BK = 64;
  constexpr int NKT = KD / BK;           // 128 K-tiles
  __shared__ char lds_raw[2 * 65536];    // 128 KB

  const int tid  = threadIdx.x;
  const int wid  = tid >> 6;
  const int lane = tid & 63;
  const int wr   = wid >> 2;             // 0..1  (M half)
  const int wc   = wid & 3;              // 0..3  (N quarter)

  // ---- 2-D concurrency-window block remap (16x16 window, 4x8 per XCD)
  constexpr int NBN    = NCOLS / BN;     // 32 (GEMM1) or 16 (GEMM2)
  constexpr int NWIN_N = NBN / 16;       // 2 or 1
  const int bid = blockIdx.x;
  const int w   = bid >> 8;
  const int sl  = bid & 255;
  const int xcd = sl & 7;
  const int cu  = sl >> 3;
  const int wm  = w / NWIN_N, wn = w % NWIN_N;
  const int bm  = wm * 16 + ((xcd >> 1) << 2) + (cu & 3);
  const int bn  = wn * 16 + ((xcd & 1) << 3) + (cu >> 2);
  const int arow0 = bm * BM;
  const int brow0 = bn * BN;

  // ---- staging sources: per-thread inverse-swizzled global ptrs, [half][chunk]
  const bf16_t* sA[2][2];
  const bf16_t* sB[2][2];
#pragma unroll
  for (int h = 0; h < 2; ++h)
#pragma unroll
    for (int i = 0; i < 2; ++i) {
      int p   = tid * 16 + i * 8192;                       // phys byte in 16KB half
      int l   = p ^ (((p >> 7) & 3) << 4) ^ (((p >> 9) & 1) << 6);
      int row = l >> 7, c = l & 127;
      sA[h][i] = Amat + (size_t)(arow0 + h * 128 + row) * KD + (c >> 1);
      sB[h][i] = Bmat + (size_t)(brow0 + h * 128 + row) * KD + (c >> 1);
    }

  // ---- ds_read byte offsets (swizzled, s=0; s=1 is ^64)
  const int j = lane >> 4;
  int aoff0[8], boff0[4];
#pragma unroll
  for (int mi = 0; mi < 8; ++mi) {
    int row = wr * 128 + mi * 16 + (lane & 15);
    aoff0[mi] = row * 128 + ((j ^ (row & 3)) << 4) + (((row >> 2) & 1) << 6);
  }
#pragma unroll
  for (int ni = 0; ni < 4; ++ni) {
    int row = wc * 64 + ni * 16 + (lane & 15);
    boff0[ni] = 32768 + row * 128 + ((j ^ (row & 3)) << 4) + (((row >> 2) & 1) << 6);
  }

  f32x4 acc[8][4];
  f32x4 zero = {0.f, 0.f, 0.f, 0.f};
#pragma unroll
  for (int mi = 0; mi < 8; ++mi)
#pragma unroll
    for (int ni = 0; ni < 4; ++ni) acc[mi][ni] = zero;

#define STAGEA(H, TAU)                                                          \
  { const size_t ko = (size_t)((TAU) & (NKT - 1)) * BK;                         \
    char* db = lds_raw + (((TAU) & 1) * 65536) + (H) * 16384 + (wid << 10);     \
    gload_lds16(sA[H][0] + ko, db);                                             \
    gload_lds16(sA[H][1] + ko, db + 8192); }
#define STAGEB(H, TAU)                                                          \
  { const size_t ko = (size_t)((TAU) & (NKT - 1)) * BK;                         \
    char* db = lds_raw + (((TAU) & 1) * 65536) + 32768 + (H) * 16384 + (wid << 10); \
    gload_lds16(sB[H][0] + ko, db);                                             \
    gload_lds16(sB[H][1] + ko, db + 8192); }

  // ---- prologue: B0(0), A0(0), A1(0), B1(0), B0(1); wait tile 0 (all but newest half)
  STAGEB(0, 0) STAGEA(0, 0) STAGEA(1, 0) STAGEB(1, 0) STAGEB(0, 1)
  asm volatile("s_waitcnt vmcnt(2)" ::: "memory");
  __builtin_amdgcn_s_barrier();

  bf16x8 bb[4];  // B fragments, live across the (h0,s)->(h1,s) phase pair

#define PHASE(BUFO, HH, SS, STG, GATE)                                          \
  {                                                                             \
    bf16x8 aq[4];                                                               \
    _Pragma("unroll")                                                           \
    for (int mi = 0; mi < 4; ++mi)                                              \
      aq[mi] = *(const bf16x8*)(lds_raw + (BUFO) +                              \
                                (aoff0[(HH) * 4 + mi] ^ ((SS) * 64)));          \
    if ((HH) == 0) {                                                            \
      _Pragma("unroll")                                                         \
      for (int ni = 0; ni < 4; ++ni)                                            \
        bb[ni] = *(const bf16x8*)(lds_raw + (BUFO) +                            \
                                  (boff0[ni] ^ ((SS) * 64)));                   \
    }                                                                           \
    STG;                                                                        \
    __builtin_amdgcn_sched_barrier(0);                                          \
    __builtin_amdgcn_s_barrier();                                               \
    asm volatile("s_waitcnt lgkmcnt(0)" ::: "memory");                          \
    __builtin_amdgcn_sched_barrier(0);                                          \
    __builtin_amdgcn_s_setprio(1);                                              \
    _Pragma("unroll")                                                           \
    for (int mi = 0; mi < 4; ++mi)                                              \
      _Pragma("unroll")                                                         \
      for (int ni = 0; ni < 4; ++ni)                                            \
        acc[(HH) * 4 + mi][ni] = __builtin_amdgcn_mfma_f32_16x16x32_bf16(       \
            aq[mi], bb[ni], acc[(HH) * 4 + mi][ni], 0, 0, 0);                   \
    __builtin_amdgcn_s_setprio(0);                                              \
    __builtin_amdgcn_sched_barrier(0);                                          \
    if (GATE) {                                                                 \
      asm volatile("s_waitcnt vmcnt(2)" ::: "memory");                          \
      __builtin_amdgcn_sched_barrier(0);                                        \
    }                                                                           \
    __builtin_amdgcn_s_barrier();                                               \
  }

  for (int t = 0; t < NKT; t += 2) {
    PHASE(0,     0, 0, STAGEA(0, t + 1), 0)
    PHASE(0,     1, 0, STAGEA(1, t + 1), 0)
    PHASE(0,     0, 1, STAGEB(1, t + 1), 0)
    PHASE(0,     1, 1, STAGEB(0, t + 2), 1)
    PHASE(65536, 0, 0, STAGEA(0, t + 2), 0)
    PHASE(65536, 1, 0, STAGEA(1, t + 2), 0)
    PHASE(65536, 0, 1, STAGEB(1, t + 2), 0)
    PHASE(65536, 1, 1, STAGEB(0, t + 3), 1)
  }
#undef PHASE
#undef STAGEA
#undef STAGEB

  // ---- epilogue.  C/D layout: row = (lane>>4)*4 + r, col = lane&15  [m89/m91]
  const int grow0 = arow0 + wr * 128 + ((lane >> 4) << 2);
  const int gcol0 = brow0 + wc * 64 + (lane & 15);

  if constexpr (MODE == 1) {
    bf16_t* __restrict__ H = (bf16_t*)Cout;
    const int kexp = brow0 >> 10;  // expert is block-uniform (256 | 1024)
#pragma unroll
    for (int mi = 0; mi < 8; ++mi) {
      float wn4[4];
#pragma unroll
      for (int r = 0; r < 4; ++r)
        wn4[r] = wgt[(size_t)(grow0 + mi * 16 + r) * KEXP + kexp];
#pragma unroll
      for (int ni = 0; ni < 4; ++ni) {
        int col = gcol0 + ni * 16;
        float bv = bias[col];
#pragma unroll
        for (int r = 0; r < 4; ++r) {
          int n = grow0 + mi * 16 + r;
          float x = acc[mi][ni][r] + bv;
          float g = 0.5f * x * (1.f + erff(x * 0.70710678118654752f));  // exact GELU
          H[(size_t)n * KD + col] = (bf16_t)(g * wn4[r]);
        }
      }
    }
  } else {
    float* __restrict__ O = (float*)Cout;
    float bcol[4][KEXP];
#pragma unroll
    for (int ni = 0; ni < 4; ++ni)
#pragma unroll
      for (int k = 0; k < KEXP; ++k)
        bcol[ni][k] = bias[(size_t)k * NCOLS + gcol0 + ni * 16];
#pragma unroll
    for (int mi = 0; mi < 8; ++mi)
#pragma unroll
      for (int r = 0; r < 4; ++r) {
        int n = grow0 + mi * 16 + r;
        const float4* wp = (const float4*)(wgt + (size_t)n * KEXP);
        float4 wa = wp[0], wb = wp[1];
        float w8[KEXP] = {wa.x, wa.y, wa.z, wa.w, wb.x, wb.y, wb.z, wb.w};
#pragma unroll
        for (int ni = 0; ni < 4; ++ni) {
          float bb2 = 0.f;
#pragma unroll
          for (int k = 0; k < KEXP; ++k) bb2 += w8[k] * bcol[ni][k];
          O[(size_t)n * NCOLS + gcol0 + ni * 16] = acc[mi][ni][r] + bb2;
        }
      }
  }
}

extern "C" void kernel_launch(void* const* d_in, const int* in_sizes, int n_in,
                              void* d_out, int out_size, void* d_ws, size_t ws_size,
                              hipStream_t stream) {
  const float* h_anchor = (const float*)d_in[0];
  const float* h_mask   = (const float*)d_in[1];
  const float* Wr       = (const float*)d_in[2];
  const float* br       = (const float*)d_in[3];
  const float* W1       = (const float*)d_in[4];
  const float* b1       = (const float*)d_in[5];
  const float* W2       = (const float*)d_in[6];
  const float* b2       = (const float*)d_in[7];
  float* out = (float*)d_out;

  char* ws = (char*)d_ws;
  bf16_t* Abf  = (bf16_t*)(ws);                       // [8192][8192] bf16 = 128 MB
  bf16_t* W1bf = (bf16_t*)(ws + ((size_t)128 << 20)); // [8192][8192] bf16 = 128 MB
  bf16_t* W2bf = (bf16_t*)(ws + ((size_t)256 << 20)); // [4096][8192] bf16 =  64 MB
  bf16_t* H1s  = (bf16_t*)(ws + ((size_t)320 << 20)); // [8192][8192] bf16 = 128 MB
  float*  wgt  = (float*) (ws + ((size_t)448 << 20)); // [8192][8]   fp32 = 256 KB

  routing_kernel<<<N_ROWS, 256, 0, stream>>>(h_mask, Wr, br, wgt);
  conv_cond_kernel<<<(N_ROWS * KD / 8) / 256, 256, 0, stream>>>(h_anchor, h_mask, Abf);
  conv_cast_kernel<<<(KEXP * FHID * 2 * DDIM / 8) / 256, 256, 0, stream>>>(W1, W1bf);
  conv_w2_kernel<<<(KEXP * DDIM * FHID / 8) / 256, 256, 0, stream>>>(W2, W2bf);

  gemm256_kernel<1, 8192><<<(N_ROWS / 256) * (KD / 256), 512, 0, stream>>>(
      Abf, W1bf, (void*)H1s, b1, wgt);
  gemm256_kernel<2, 4096><<<(N_ROWS / 256) * (DDIM / 256), 512, 0, stream>>>(
      H1s, W2bf, (void*)out, b2, wgt);
}

// Round 8
// 1522.159 us; speedup vs baseline: 1.6524x; 1.0078x over previous
//
#include <hip/hip_runtime.h>
#include <hip/hip_bf16.h>
#include <math.h>

typedef __bf16 bf16_t;
typedef __bf16 bf16x8 __attribute__((ext_vector_type(8)));
typedef float  f32x4  __attribute__((ext_vector_type(4)));

#define AS1 __attribute__((address_space(1)))
#define AS3 __attribute__((address_space(3)))

__device__ __forceinline__ void gload_lds16(const bf16_t* g, char* l) {
  __builtin_amdgcn_global_load_lds((const AS1 void*)g, (AS3 void*)l, 16, 0, 0);
}

static constexpr int N_ROWS = 8192;
static constexpr int DDIM   = 4096;
static constexpr int KEXP   = 8;
static constexpr int FHID   = 1024;
static constexpr int KD     = 8192;   // inner dim of both GEMMs (2D and K*F)

// ---------------- routing: weights = softmax(h_mask @ Wr^T + br) ----------------
__global__ __launch_bounds__(256)
void routing_kernel(const float* __restrict__ hm, const float* __restrict__ Wr,
                    const float* __restrict__ br, float* __restrict__ wgt) {
  const int n = blockIdx.x;
  const int t = threadIdx.x;
  const int wid = t >> 6;
  const float4* row = (const float4*)(hm + (size_t)n * DDIM);
  float4 x[4];
#pragma unroll
  for (int j = 0; j < 4; ++j) x[j] = row[t + j * 256];
  __shared__ float red[KEXP][4];
  float part[KEXP];
#pragma unroll
  for (int k = 0; k < KEXP; ++k) {
    const float4* wr = (const float4*)(Wr + (size_t)k * DDIM);
    float s = 0.f;
#pragma unroll
    for (int j = 0; j < 4; ++j) {
      float4 w4 = wr[t + j * 256];
      s += x[j].x * w4.x + x[j].y * w4.y + x[j].z * w4.z + x[j].w * w4.w;
    }
#pragma unroll
    for (int off = 32; off > 0; off >>= 1) s += __shfl_down(s, off);
    part[k] = s;
  }
  if ((t & 63) == 0) {
#pragma unroll
    for (int k = 0; k < KEXP; ++k) red[k][wid] = part[k];
  }
  __syncthreads();
  if (t == 0) {
    float lg[KEXP];
    float mx = -1e30f;
#pragma unroll
    for (int k = 0; k < KEXP; ++k) {
      lg[k] = red[k][0] + red[k][1] + red[k][2] + red[k][3] + br[k];
      mx = fmaxf(mx, lg[k]);
    }
    float sum = 0.f;
#pragma unroll
    for (int k = 0; k < KEXP; ++k) { lg[k] = expf(lg[k] - mx); sum += lg[k]; }
    float inv = 1.f / sum;
#pragma unroll
    for (int k = 0; k < KEXP; ++k) wgt[(size_t)n * KEXP + k] = lg[k] * inv;
  }
}

// ---------------- conversions to bf16 ----------------
__device__ __forceinline__ bf16x8 cvt8(float4 f0, float4 f1) {
  bf16x8 o;
  o[0] = (bf16_t)f0.x; o[1] = (bf16_t)f0.y; o[2] = (bf16_t)f0.z; o[3] = (bf16_t)f0.w;
  o[4] = (bf16_t)f1.x; o[5] = (bf16_t)f1.y; o[6] = (bf16_t)f1.z; o[7] = (bf16_t)f1.w;
  return o;
}

// A[n][0:4096]=h_anchor, A[n][4096:8192]=h_mask   (concat, bf16)
__global__ __launch_bounds__(256)
void conv_cond_kernel(const float* __restrict__ ha, const float* __restrict__ hm,
                      bf16_t* __restrict__ A) {
  size_t c = (size_t)blockIdx.x * 256 + threadIdx.x;  // chunk of 8 elements
  int n   = (int)(c >> 10);                           // 1024 chunks per row of 8192
  int pos = ((int)c & 1023) * 8;
  const float* src = (pos < DDIM) ? ha + (size_t)n * DDIM + pos
                                  : hm + (size_t)n * DDIM + (pos - DDIM);
  float4 f0 = ((const float4*)src)[0];
  float4 f1 = ((const float4*)src)[1];
  *(bf16x8*)(A + c * 8) = cvt8(f0, f1);
}

// straight fp32 -> bf16 cast (W1: already [K*F][2D] row-major)
__global__ __launch_bounds__(256)
void conv_cast_kernel(const float* __restrict__ in, bf16_t* __restrict__ out) {
  size_t c = (size_t)blockIdx.x * 256 + threadIdx.x;
  float4 f0 = ((const float4*)(in + c * 8))[0];
  float4 f1 = ((const float4*)(in + c * 8))[1];
  *(bf16x8*)(out + c * 8) = cvt8(f0, f1);
}

// W2[k][d][f] -> B2[d][k*F+f]  (bf16)
__global__ __launch_bounds__(256)
void conv_w2_kernel(const float* __restrict__ W2, bf16_t* __restrict__ B2) {
  size_t c = (size_t)blockIdx.x * 256 + threadIdx.x;  // over K*D*F/8
  int f8 = (int)(c & 127);
  int d  = (int)((c >> 7) & 4095);
  int k  = (int)(c >> 19);
  const float* src = W2 + ((size_t)k * DDIM + d) * FHID + f8 * 8;
  float4 f0 = ((const float4*)src)[0];
  float4 f1 = ((const float4*)src)[1];
  *(bf16x8*)(B2 + (size_t)d * KD + k * FHID + f8 * 8) = cvt8(f0, f1);
}

// ---------------- 256x256 8-phase GEMM, v8: lgkm-countdown phases ----------------
// BK=64, 2 LDS buffers (64 KB each), 8 waves (2Mx4N), 512 thr, 1 barrier/phase.
// Phase (h,s): STAGE(2 gloads) ; ds_reads pinned order aq0,[bb0-3],aq1,aq2,aq3 ;
//   lgkm(3) MFMA(aq0) ; lgkm(2) MFMA(aq1) ; lgkm(1) MFMA(aq2) ; lgkm(0) MFMA(aq3) ;
//   [gate vmcnt(2)] ; s_barrier.
// The trailing 3 reads drain UNDER the MFMA clusters (intra-phase LDS/MFMA overlap,
// zero extra registers - r5/r6 lesson: frag-set prefetch trades VGPR for nothing).
// Single barrier/phase is safe: every phase drains lgkm to 0 before its end barrier
// (reads RETIRED pre-barrier), and every stage is issued post-barrier targeting a
// region whose last read retired >=1 barrier earlier (rotation audit); staged-data
// visibility is published by the vmcnt(2)+barrier gates (phases 4/8 of each body).
// Stage rotation (slot->half): A0(t+1),A1(t+1),B1(t+1),B0(t+2)+gate,
//                              A0(t+2),A1(t+2),B1(t+2),B0(t+3)+gate. Modular wrap.
// LDS swizzle: involution p ^= ((p>>7)&3)<<4 ^ ((p>>9)&1)<<6; inverse on global
// source + forward on ds_read (rule #21). Block remap: 16x16 windows, 4x8 per XCD.
// MODE 1: epilogue = +b1, exact GELU, *w[n][col>>10], store bf16 (H1s)
// MODE 2: epilogue = + sum_k w[n][k]*b2[k][col], store fp32 (out)
template <int MODE, int NCOLS>
__global__ __launch_bounds__(512, 2)
void gemm256_kernel(const bf16_t* __restrict__ Amat, const bf16_t* __restrict__ Bmat,
                    void* __restrict__ Cout, const float* __restrict__ bias,
                    const float* __restrict__ wgt) {
  constexpr int BM = 256, BN = 256, BK = 64;
  constexpr int NKT = KD / BK;           // 128 K-tiles
  __shared__ char lds_raw[2 * 65536];    // 128 KB

  const int tid  = threadIdx.x;
  const int wid  = tid >> 6;
  const int lane = tid & 63;
  const int wr   = wid >> 2;             // 0..1  (M half)
  const int wc   = wid & 3;              // 0..3  (N quarter)

  // ---- 2-D concurrency-window block remap (16x16 window, 4x8 per XCD)
  constexpr int NBN    = NCOLS / BN;     // 32 (GEMM1) or 16 (GEMM2)
  constexpr int NWIN_N = NBN / 16;       // 2 or 1
  const int bid = blockIdx.x;
  const int w   = bid >> 8;
  const int sl  = bid & 255;
  const int xcd = sl & 7;
  const int cu  = sl >> 3;
  const int wm  = w / NWIN_N, wn = w % NWIN_N;
  const int bm  = wm * 16 + ((xcd >> 1) << 2) + (cu & 3);
  const int bn  = wn * 16 + ((xcd & 1) << 3) + (cu >> 2);
  const int arow0 = bm * BM;
  const int brow0 = bn * BN;

  // ---- staging sources: per-thread inverse-swizzled global ptrs, [half][chunk]
  const bf16_t* sA[2][2];
  const bf16_t* sB[2][2];
#pragma unroll
  for (int h = 0; h < 2; ++h)
#pragma unroll
    for (int i = 0; i < 2; ++i) {
      int p   = tid * 16 + i * 8192;                       // phys byte in 16KB half
      int l   = p ^ (((p >> 7) & 3) << 4) ^ (((p >> 9) & 1) << 6);
      int row = l >> 7, c = l & 127;
      sA[h][i] = Amat + (size_t)(arow0 + h * 128 + row) * KD + (c >> 1);
      sB[h][i] = Bmat + (size_t)(brow0 + h * 128 + row) * KD + (c >> 1);
    }

  // ---- ds_read byte offsets (swizzled, s=0; s=1 is ^64)
  const int j = lane >> 4;
  int aoff0[8], boff0[4];
#pragma unroll
  for (int mi = 0; mi < 8; ++mi) {
    int row = wr * 128 + mi * 16 + (lane & 15);
    aoff0[mi] = row * 128 + ((j ^ (row & 3)) << 4) + (((row >> 2) & 1) << 6);
  }
#pragma unroll
  for (int ni = 0; ni < 4; ++ni) {
    int row = wc * 64 + ni * 16 + (lane & 15);
    boff0[ni] = 32768 + row * 128 + ((j ^ (row & 3)) << 4) + (((row >> 2) & 1) << 6);
  }

  f32x4 acc[8][4];
  f32x4 zero = {0.f, 0.f, 0.f, 0.f};
#pragma unroll
  for (int mi = 0; mi < 8; ++mi)
#pragma unroll
    for (int ni = 0; ni < 4; ++ni) acc[mi][ni] = zero;

#define STAGEA(H, TAU)                                                          \
  { const size_t ko = (size_t)((TAU) & (NKT - 1)) * BK;                         \
    char* db = lds_raw + (((TAU) & 1) * 65536) + (H) * 16384 + (wid << 10);     \
    gload_lds16(sA[H][0] + ko, db);                                             \
    gload_lds16(sA[H][1] + ko, db + 8192); }
#define STAGEB(H, TAU)                                                          \
  { const size_t ko = (size_t)((TAU) & (NKT - 1)) * BK;                         \
    char* db = lds_raw + (((TAU) & 1) * 65536) + 32768 + (H) * 16384 + (wid << 10); \
    gload_lds16(sB[H][0] + ko, db);                                             \
    gload_lds16(sB[H][1] + ko, db + 8192); }

  // ---- prologue: B0(0), A0(0), A1(0), B1(0), B0(1); wait all but newest half
  STAGEB(0, 0) STAGEA(0, 0) STAGEA(1, 0) STAGEB(1, 0) STAGEB(0, 1)
  asm volatile("s_waitcnt vmcnt(2)" ::: "memory");
  __builtin_amdgcn_s_barrier();
  __builtin_amdgcn_sched_barrier(0);

  bf16x8 bb[4];  // B fragments, live across the (h0,s)->(h1,s) phase pair

#define SB __builtin_amdgcn_sched_barrier(0);
#define CLUSTER(MI, HH)                                                         \
    _Pragma("unroll")                                                           \
    for (int ni = 0; ni < 4; ++ni)                                              \
      acc[(HH) * 4 + (MI)][ni] = __builtin_amdgcn_mfma_f32_16x16x32_bf16(       \
          aq[MI], bb[ni], acc[(HH) * 4 + (MI)][ni], 0, 0, 0);

#define PHASE(BUFO, HH, SS, STG, GATE)                                          \
  {                                                                             \
    STG;                                                                        \
    SB                                                                          \
    bf16x8 aq[4];                                                               \
    aq[0] = *(const bf16x8*)(lds_raw + (BUFO) + (aoff0[(HH)*4+0] ^ ((SS)*64))); \
    SB                                                                          \
    if ((HH) == 0) {                                                            \
      _Pragma("unroll")                                                         \
      for (int ni = 0; ni < 4; ++ni)                                            \
        bb[ni] = *(const bf16x8*)(lds_raw + (BUFO) + (boff0[ni] ^ ((SS)*64)));  \
      SB                                                                        \
    }                                                                           \
    aq[1] = *(const bf16x8*)(lds_raw + (BUFO) + (aoff0[(HH)*4+1] ^ ((SS)*64))); \
    SB                                                                          \
    aq[2] = *(const bf16x8*)(lds_raw + (BUFO) + (aoff0[(HH)*4+2] ^ ((SS)*64))); \
    SB                                                                          \
    aq[3] = *(const bf16x8*)(lds_raw + (BUFO) + (aoff0[(HH)*4+3] ^ ((SS)*64))); \
    SB                                                                          \
    __builtin_amdgcn_s_setprio(1);                                              \
    asm volatile("s_waitcnt lgkmcnt(3)" ::: "memory");                          \
    SB                                                                          \
    CLUSTER(0, HH)                                                              \
    SB                                                                          \
    asm volatile("s_waitcnt lgkmcnt(2)" ::: "memory");                          \
    SB                                                                          \
    CLUSTER(1, HH)                                                              \
    SB                                                                          \
    asm volatile("s_waitcnt lgkmcnt(1)" ::: "memory");                          \
    SB                                                                          \
    CLUSTER(2, HH)                                                              \
    SB                                                                          \
    asm volatile("s_waitcnt lgkmcnt(0)" ::: "memory");                          \
    SB                                                                          \
    CLUSTER(3, HH)                                                              \
    SB                                                                          \
    __builtin_amdgcn_s_setprio(0);                                              \
    if (GATE) {                                                                 \
      asm volatile("s_waitcnt vmcnt(2)" ::: "memory");                          \
      SB                                                                        \
    }                                                                           \
    __builtin_amdgcn_s_barrier();                                               \
    SB                                                                          \
  }

  for (int t = 0; t < NKT; t += 2) {
    PHASE(0,     0, 0, STAGEA(0, t + 1), 0)
    PHASE(0,     1, 0, STAGEA(1, t + 1), 0)
    PHASE(0,     0, 1, STAGEB(1, t + 1), 0)
    PHASE(0,     1, 1, STAGEB(0, t + 2), 1)
    PHASE(65536, 0, 0, STAGEA(0, t + 2), 0)
    PHASE(65536, 1, 0, STAGEA(1, t + 2), 0)
    PHASE(65536, 0, 1, STAGEB(1, t + 2), 0)
    PHASE(65536, 1, 1, STAGEB(0, t + 3), 1)
  }
#undef PHASE
#undef CLUSTER
#undef SB
#undef STAGEA
#undef STAGEB

  // ---- epilogue.  C/D layout: row = (lane>>4)*4 + r, col = lane&15  [m89/m91]
  const int grow0 = arow0 + wr * 128 + ((lane >> 4) << 2);
  const int gcol0 = brow0 + wc * 64 + (lane & 15);

  if constexpr (MODE == 1) {
    bf16_t* __restrict__ H = (bf16_t*)Cout;
    const int kexp = brow0 >> 10;  // expert is block-uniform (256 | 1024)
#pragma unroll
    for (int mi = 0; mi < 8; ++mi) {
      float wn4[4];
#pragma unroll
      for (int r = 0; r < 4; ++r)
        wn4[r] = wgt[(size_t)(grow0 + mi * 16 + r) * KEXP + kexp];
#pragma unroll
      for (int ni = 0; ni < 4; ++ni) {
        int col = gcol0 + ni * 16;
        float bv = bias[col];
#pragma unroll
        for (int r = 0; r < 4; ++r) {
          int n = grow0 + mi * 16 + r;
          float x = acc[mi][ni][r] + bv;
          float g = 0.5f * x * (1.f + erff(x * 0.70710678118654752f));  // exact GELU
          H[(size_t)n * KD + col] = (bf16_t)(g * wn4[r]);
        }
      }
    }
  } else {
    float* __restrict__ O = (float*)Cout;
    float bcol[4][KEXP];
#pragma unroll
    for (int ni = 0; ni < 4; ++ni)
#pragma unroll
      for (int k = 0; k < KEXP; ++k)
        bcol[ni][k] = bias[(size_t)k * NCOLS + gcol0 + ni * 16];
#pragma unroll
    for (int mi = 0; mi < 8; ++mi)
#pragma unroll
      for (int r = 0; r < 4; ++r) {
        int n = grow0 + mi * 16 + r;
        const float4* wp = (const float4*)(wgt + (size_t)n * KEXP);
        float4 wa = wp[0], wb = wp[1];
        float w8[KEXP] = {wa.x, wa.y, wa.z, wa.w, wb.x, wb.y, wb.z, wb.w};
#pragma unroll
        for (int ni = 0; ni < 4; ++ni) {
          float bb2 = 0.f;
#pragma unroll
          for (int k = 0; k < KEXP; ++k) bb2 += w8[k] * bcol[ni][k];
          O[(size_t)n * NCOLS + gcol0 + ni * 16] = acc[mi][ni][r] + bb2;
        }
      }
  }
}

extern "C" void kernel_launch(void* const* d_in, const int* in_sizes, int n_in,
                              void* d_out, int out_size, void* d_ws, size_t ws_size,
                              hipStream_t stream) {
  const float* h_anchor = (const float*)d_in[0];
  const float* h_mask   = (const float*)d_in[1];
  const float* Wr       = (const float*)d_in[2];
  const float* br       = (const float*)d_in[3];
  const float* W1       = (const float*)d_in[4];
  const float* b1       = (const float*)d_in[5];
  const float* W2       = (const float*)d_in[6];
  const float* b2       = (const float*)d_in[7];
  float* out = (float*)d_out;

  char* ws = (char*)d_ws;
  bf16_t* Abf  = (bf16_t*)(ws);                       // [8192][8192] bf16 = 128 MB
  bf16_t* W1bf = (bf16_t*)(ws + ((size_t)128 << 20)); // [8192][8192] bf16 = 128 MB
  bf16_t* W2bf = (bf16_t*)(ws + ((size_t)256 << 20)); // [4096][8192] bf16 =  64 MB
  bf16_t* H1s  = (bf16_t*)(ws + ((size_t)320 << 20)); // [8192][8192] bf16 = 128 MB
  float*  wgt  = (float*) (ws + ((size_t)448 << 20)); // [8192][8]   fp32 = 256 KB

  routing_kernel<<<N_ROWS, 256, 0, stream>>>(h_mask, Wr, br, wgt);
  conv_cond_kernel<<<(N_ROWS * KD / 8) / 256, 256, 0, stream>>>(h_anchor, h_mask, Abf);
  conv_cast_kernel<<<(KEXP * FHID * 2 * DDIM / 8) / 256, 256, 0, stream>>>(W1, W1bf);
  conv_w2_kernel<<<(KEXP * DDIM * FHID / 8) / 256, 256, 0, stream>>>(W2, W2bf);

  gemm256_kernel<1, 8192><<<(N_ROWS / 256) * (KD / 256), 512, 0, stream>>>(
      Abf, W1bf, (void*)H1s, b1, wgt);
  gemm256_kernel<2, 4096><<<(N_ROWS / 256) * (DDIM / 256), 512, 0, stream>>>(
      H1s, W2bf, (void*)out, b2, wgt);
}